// Round 2
// baseline (2289.554 us; speedup 1.0000x reference)
//
#include <hip/hip_runtime.h>
#include <hip/hip_bf16.h>

#define FIN 512
#define HID 16
#define NCLS 40

typedef unsigned short u16;
typedef __attribute__((ext_vector_type(8))) short short8;
typedef __attribute__((ext_vector_type(4))) float f32x4;

__device__ __forceinline__ float bf2f(u16 u) {
    return __uint_as_float(((unsigned int)u) << 16);
}
__device__ __forceinline__ u16 f2bf_rne(float f) {
    unsigned int u = __float_as_uint(f);
    unsigned int r = u + 0x7FFFu + ((u >> 16) & 1u);
    return (u16)(r >> 16);
}
// load element i of a float input that is either bf16 (isf32=0) or fp32 (isf32=1)
__device__ __forceinline__ float load_in(const void* p, size_t i, int isf32) {
    return isf32 ? ((const float*)p)[i] : bf2f(((const u16*)p)[i]);
}

// ---------------- dtype probe: bf16-packed vs fp32 words --------------------------
__global__ void probe_kernel(const unsigned int* __restrict__ x, int* __restrict__ flag)
{
    int cnt = 0;
    for (int i = threadIdx.x; i < 256; i += 64) {
        unsigned int w = x[i];
        float v = __uint_as_float((w & 0xFFFFu) << 16);
        float a = fabsf(v);
        if (a >= 6.1e-5f && a <= 64.f) cnt++;
    }
    #pragma unroll
    for (int off = 32; off >= 1; off >>= 1) cnt += __shfl_xor(cnt, off, 64);
    if (threadIdx.x == 0) *flag = (cnt < 128) ? 1 : 0;   // 1 => inputs are fp32
}

// ---------------- GEMM1: h = relu(x @ W1 + b1); rn = 1/max(||h_row||, eps) --------
__global__ __launch_bounds__(256) void gemm1_mfma(
    const void* __restrict__ x, const void* __restrict__ W1, const void* __restrict__ b1,
    float* __restrict__ h, float* __restrict__ rn, int ngroups, int N,
    const int* __restrict__ flagp)
{
    const int isf32 = *flagp;
    const int lane = threadIdx.x & 63;
    const int m    = lane & 15;      // B col / D col
    const int quad = lane >> 4;
    const int wid  = blockIdx.x * 4 + (threadIdx.x >> 6);
    const int nw   = gridDim.x * 4;

    // B-frag for tile kb: lane holds B[k=kb*32+quad*8+j][n=m]  (j=0..7)
    short8 bfrag[16];
    #pragma unroll
    for (int kb = 0; kb < 16; ++kb)
        #pragma unroll
        for (int j = 0; j < 8; ++j) {
            size_t idx = (size_t)(kb*32 + quad*8 + j)*HID + m;
            bfrag[kb][j] = isf32 ? (short)f2bf_rne(((const float*)W1)[idx])
                                 : (short)((const u16*)W1)[idx];
        }
    const float bias = load_in(b1, m, isf32);

    for (int g = wid; g < ngroups; g += nw) {
        // clamp row for OOB-safety when N % 16 != 0 (stores are guarded below)
        size_t row = (size_t)g*16 + m;
        if (row >= (size_t)N) row = N - 1;
        f32x4 acc = {0.f, 0.f, 0.f, 0.f};
        if (isf32) {
            // vectorized: each lane owns 32B contiguous per K-block -> 2x float4
            const float* xb = (const float*)x + row*FIN + quad*8;
            #pragma unroll
            for (int kb = 0; kb < 16; ++kb) {
                f32x4 v0 = *(const f32x4*)(xb + kb*32);
                f32x4 v1 = *(const f32x4*)(xb + kb*32 + 4);
                short8 a;
                a[0] = (short)f2bf_rne(v0[0]); a[1] = (short)f2bf_rne(v0[1]);
                a[2] = (short)f2bf_rne(v0[2]); a[3] = (short)f2bf_rne(v0[3]);
                a[4] = (short)f2bf_rne(v1[0]); a[5] = (short)f2bf_rne(v1[1]);
                a[6] = (short)f2bf_rne(v1[2]); a[7] = (short)f2bf_rne(v1[3]);
                acc = __builtin_amdgcn_mfma_f32_16x16x32_bf16(a, bfrag[kb], acc, 0, 0, 0);
            }
        } else {
            const u16* xb = (const u16*)x + row*FIN + quad*8;
            #pragma unroll
            for (int kb = 0; kb < 16; ++kb) {
                short8 a = *(const short8*)(xb + kb*32);
                acc = __builtin_amdgcn_mfma_f32_16x16x32_bf16(a, bfrag[kb], acc, 0, 0, 0);
            }
        }
        // D: row = quad*4+i, col = m   [verified layout, m89/m91]
        #pragma unroll
        for (int i = 0; i < 4; ++i) {
            int r = quad*4 + i;
            float v = fmaxf(acc[i] + bias, 0.f);
            size_t orow = (size_t)g*16 + r;
            if (orow < (size_t)N) h[orow*HID + m] = v;
            float ss = v*v;
            ss += __shfl_xor(ss, 1, 64);
            ss += __shfl_xor(ss, 2, 64);
            ss += __shfl_xor(ss, 4, 64);
            ss += __shfl_xor(ss, 8, 64);
            if (m == 0 && orow < (size_t)N) rn[orow] = 1.0f / fmaxf(sqrtf(ss), 1e-12f);
        }
    }
}

// ---------------- CSR build (grouped by dst) --------------------------------------
// Two paths chosen by ws_size at launch:
//  (a) bucket sort (needs +E*4 bytes "pairs"): low write amplification
//  (b) legacy direct scatter fill (round-0 behavior): fits the minimal workspace
__global__ __launch_bounds__(256) void count_kernel(
    const int* __restrict__ dst, int* __restrict__ counts, int* __restrict__ bcnt, int E)
{
    int e = blockIdx.x * 256 + threadIdx.x;
    if (e < E) {
        int d = dst[e];
        atomicAdd(&counts[d], 1);
        atomicAdd(&bcnt[d >> 7], 1);
    }
}

__global__ __launch_bounds__(256) void alloc_kernel(
    const int* __restrict__ counts, int* __restrict__ row_start,
    int* __restrict__ gcur, int N)
{
    int n = blockIdx.x * 256 + threadIdx.x;
    int lane = threadIdx.x & 63;
    int cnt = (n < N) ? counts[n] : 0;
    int s = cnt;
    #pragma unroll
    for (int d = 1; d <= 32; d <<= 1) {
        int t = __shfl_up(s, d, 64);
        if (lane >= d) s += t;
    }
    int total = __shfl(s, 63, 64);
    int base = 0;
    if (lane == 0) base = atomicAdd(gcur, total);
    base = __shfl(base, 0, 64);
    if (n < N) row_start[n] = base + s - cnt;
}

// legacy path: direct random scatter into csr
__global__ __launch_bounds__(256) void fill_kernel(
    const int* __restrict__ src, const int* __restrict__ dst,
    const int* __restrict__ row_start, int* __restrict__ cursor,
    int* __restrict__ csr, int E)
{
    int e = blockIdx.x * 256 + threadIdx.x;
    if (e < E) {
        int d = dst[e];
        int p = atomicAdd(&cursor[d], 1);
        csr[row_start[d] + p] = src[e];
    }
}

// bucket path: scatter packed (local_dst<<24 | src) into exact-sized bucket segs
__global__ __launch_bounds__(256) void scatter_kernel(
    const int* __restrict__ src, const int* __restrict__ dst,
    const int* __restrict__ bbase, int* __restrict__ bcur,
    int* __restrict__ pairs, int E)
{
    int e = blockIdx.x * 256 + threadIdx.x;
    if (e < E) {
        int d = dst[e];
        int s = src[e];
        int b = d >> 7;
        int p = atomicAdd(&bcur[b], 1);
        // pack: local dst (7b) in [31:24], src (24b) in [23:0]; requires N <= 2^24
        pairs[bbase[b] + p] = ((d & 127) << 24) | s;
    }
}

__global__ __launch_bounds__(256) void bucket_fill_kernel(
    const int* __restrict__ pairs, const int* __restrict__ bbase,
    const int* __restrict__ bcnt, const int* __restrict__ row_start,
    int* __restrict__ csr, int N)
{
    int b = blockIdx.x;
    int n0 = b << 7;
    __shared__ int lrs[128];
    __shared__ int lcur[128];
    int t = threadIdx.x;
    if (t < 128) {
        lcur[t] = 0;
        int n = n0 + t;
        lrs[t] = (n < N) ? row_start[n] : 0;
    }
    __syncthreads();
    int base = bbase[b];
    int cnt  = bcnt[b];
    for (int i = t; i < cnt; i += 256) {
        int w = pairs[base + i];
        int s = w & 0xFFFFFF;
        int local = ((unsigned)w) >> 24;
        int p = atomicAdd(&lcur[local], 1);
        csr[lrs[local] + p] = s;
    }
}

// ---------------- AGNN propagation: one wave per dst node -------------------------
// Softmax via CONSTANT shift M = |beta| (alpha in [-|beta|,|beta|] by C-S):
// shift-invariant => identical to reference, branch-free, exp args <= 0.
__global__ __launch_bounds__(256) void prop_kernel(
    const float* __restrict__ f, const float* __restrict__ rn,
    const int* __restrict__ row_start, const int* __restrict__ counts,
    const int* __restrict__ csr, const void* __restrict__ beta_ptr, int use_beta,
    float* __restrict__ out, float* __restrict__ rn_out, int N,
    const int* __restrict__ flagp)
{
    int wid = blockIdx.x * 4 + (threadIdx.x >> 6);
    if (wid >= N) return;
    const int isf32 = *flagp;
    const int lane = threadIdx.x & 63;
    const int c = lane & 15;
    const int g = lane >> 4;
    const int n = wid;

    const float beta = use_beta ? load_in(beta_ptr, 0, isf32) : 1.0f;
    const float M = fabsf(beta);
    const float fn_c = f[(size_t)n*HID + c];
    const float rn_n = rn[n];
    const int base = row_start[n];
    const int deg  = counts[n];

    float s = 0.f, acc = 0.f;
    for (int j = g; j < deg + 1; j += 4) {
        int idx = base + ((j < deg) ? j : 0);   // address always in-bounds
        int v = csr[idx];
        int src = (j < deg) ? v : n;            // virtual self-loop at j==deg
        float fs = f[(size_t)src*HID + c];
        float rs = rn[src];
        float p = fs * fn_c;                    // group-wide dot (16 lanes)
        p += __shfl_xor(p, 1, 64);
        p += __shfl_xor(p, 2, 64);
        p += __shfl_xor(p, 4, 64);
        p += __shfl_xor(p, 8, 64);
        float alpha = beta * p * rs * rn_n;     // in [-|beta|, |beta|]
        float t = __expf(alpha - M);            // in (0, 1]
        s   += t;
        acc += t * fs;
    }
    #pragma unroll
    for (int off = 16; off <= 32; off <<= 1) {  // merge the 4 groups
        s   += __shfl_xor(s, off, 64);
        acc += __shfl_xor(acc, off, 64);
    }
    float o = acc / s;
    if (lane < HID) out[(size_t)n*HID + lane] = o;
    float p2 = o * o;
    p2 += __shfl_xor(p2, 1, 64);
    p2 += __shfl_xor(p2, 2, 64);
    p2 += __shfl_xor(p2, 4, 64);
    p2 += __shfl_xor(p2, 8, 64);
    if (lane == 0) rn_out[n] = 1.0f / fmaxf(sqrtf(p2), 1e-12f);
}

// ---------------- classifier + log_softmax ----------------------------------------
__global__ __launch_bounds__(256) void classify_kernel(
    const float* __restrict__ h2, const void* __restrict__ W2,
    const void* __restrict__ b2, void* __restrict__ out, int N,
    const int* __restrict__ flagp)
{
    const int isf32 = *flagp;
    __shared__ float w2s[HID * NCLS];
    __shared__ float b2s[NCLS];
    for (int i = threadIdx.x; i < HID * NCLS; i += 256) w2s[i] = load_in(W2, i, isf32);
    if (threadIdx.x < NCLS) b2s[threadIdx.x] = load_in(b2, threadIdx.x, isf32);
    __syncthreads();

    int wid = blockIdx.x * 4 + (threadIdx.x >> 6);
    if (wid >= N) return;
    const int lane = threadIdx.x & 63;
    const int n = wid;

    float acc = -3.0e38f;
    if (lane < NCLS) {
        acc = b2s[lane];
        #pragma unroll
        for (int k = 0; k < HID; ++k)
            acc += h2[(size_t)n*HID + k] * w2s[k*NCLS + lane];
    }
    float mx = acc;
    #pragma unroll
    for (int off = 32; off >= 1; off >>= 1)
        mx = fmaxf(mx, __shfl_xor(mx, off, 64));
    float e = (lane < NCLS) ? __expf(acc - mx) : 0.f;
    float sum = e;
    #pragma unroll
    for (int off = 32; off >= 1; off >>= 1)
        sum += __shfl_xor(sum, off, 64);
    if (lane < NCLS) {
        float res = acc - mx - __logf(sum);
        if (!(res == res) || fabsf(res) > 1e30f) res = 0.f;
        size_t oi = (size_t)n*NCLS + lane;
        if (isf32) ((float*)out)[oi] = res;
        else       ((u16*)out)[oi]  = f2bf_rne(res);
    }
}

extern "C" void kernel_launch(void* const* d_in, const int* in_sizes, int n_in,
                              void* d_out, int out_size, void* d_ws, size_t ws_size,
                              hipStream_t stream)
{
    const void* x     = d_in[0];
    const int*  ei    = (const int*)d_in[1];
    const void* W1    = d_in[2];
    const void* b1    = d_in[3];
    const void* W2    = d_in[4];
    const void* b2    = d_in[5];
    const void* beta2 = d_in[6];

    const int N = in_sizes[0] / FIN;
    const int E = in_sizes[1] / 2;
    const int NB = (N + 127) >> 7;           // 128-node buckets
    const int* srcv = ei;
    const int* dstv = ei + E;

    char* ws = (char*)d_ws;
    size_t off = 0;
    auto take = [&](size_t bytes) -> char* {
        char* p = ws + off;
        off += (bytes + 255) & ~(size_t)255;
        return p;
    };
    // ---- minimal (round-0-sized) layout first: ~21.2 MB ----
    float* h0        = (float*)take((size_t)N * HID * 4);
    float* rn0       = (float*)take((size_t)N * 4);
    // ---- zeroed range start ----
    int*   counts    = (int*)take((size_t)N * 4);
    int*   cursor    = (int*)take((size_t)N * 4);   // legacy path only
    int*   bcnt      = (int*)take((size_t)NB * 4);
    int*   bcur      = (int*)take((size_t)NB * 4);
    int*   gcur      = (int*)take(256);   // [0]=csr alloc, [16]=pairs alloc
    // ---- zeroed range end ----
    int*   row_start = (int*)take((size_t)N * 4);
    int*   bbase     = (int*)take((size_t)NB * 4);
    int*   csr       = (int*)take((size_t)(E + 64) * 4);
    int*   flag      = (int*)take(256);                   // NOT in memset range
    // ---- optional bucket-sort buffer: only used if it fits ws_size ----
    int*   pairs     = (int*)take((size_t)(E + 64) * 4);
    const int use_bucket = (off <= ws_size) ? 1 : 0;

    // h1/rn1 live in d_out (dead before classify overwrites it); worst-case
    // d_out is bf16 -> 8MB >= 6.8MB needed.
    float* h1  = (float*)d_out;
    float* rn1 = (float*)((char*)d_out + (size_t)N * HID * 4);
    float* h2  = h0;   // h0 dead after prop1
    float* rn2 = rn0;  // sink for prop2's rnorm (unused)

    size_t zbytes = (size_t)((char*)gcur - (char*)counts) + 256;
    hipMemsetAsync(counts, 0, zbytes, stream);

    probe_kernel<<<1, 64, 0, stream>>>((const unsigned int*)x, flag);

    const int ngroups = (N + 15) / 16;
    gemm1_mfma<<<782, 256, 0, stream>>>(x, W1, b1, h0, rn0, ngroups, N, flag);

    int eb = (E + 255) / 256;
    int nb = (N + 255) / 256;
    int bb = (NB + 255) / 256;
    int wb = (N + 3) / 4;                       // one wave per node
    count_kernel<<<eb, 256, 0, stream>>>(dstv, counts, bcnt, E);
    alloc_kernel<<<nb, 256, 0, stream>>>(counts, row_start, gcur, N);
    if (use_bucket) {
        alloc_kernel<<<bb, 256, 0, stream>>>(bcnt, bbase, gcur + 16, NB);
        scatter_kernel<<<eb, 256, 0, stream>>>(srcv, dstv, bbase, bcur, pairs, E);
        bucket_fill_kernel<<<NB, 256, 0, stream>>>(pairs, bbase, bcnt, row_start, csr, N);
    } else {
        fill_kernel<<<eb, 256, 0, stream>>>(srcv, dstv, row_start, cursor, csr, E);
    }

    prop_kernel<<<wb, 256, 0, stream>>>(h0, rn0, row_start, counts, csr,
                                        b1, 0, h1, rn1, N, flag);
    prop_kernel<<<wb, 256, 0, stream>>>(h1, rn1, row_start, counts, csr,
                                        beta2, 1, h2, rn2, N, flag);

    classify_kernel<<<wb, 256, 0, stream>>>(h2, W2, b2, d_out, N, flag);
}

// Round 3
// 863.872 us; speedup vs baseline: 2.6503x; 2.6503x over previous
//
#include <hip/hip_runtime.h>
#include <hip/hip_bf16.h>

#define FIN 512
#define HID 16
#define NCLS 40
#define MAXNB 1024   // max buckets supported by LDS partition path

typedef unsigned short u16;
typedef __attribute__((ext_vector_type(8))) short short8;
typedef __attribute__((ext_vector_type(4))) float f32x4;

__device__ __forceinline__ float bf2f(u16 u) {
    return __uint_as_float(((unsigned int)u) << 16);
}
__device__ __forceinline__ u16 f2bf_rne(float f) {
    unsigned int u = __float_as_uint(f);
    unsigned int r = u + 0x7FFFu + ((u >> 16) & 1u);
    return (u16)(r >> 16);
}
// load element i of a float input that is either bf16 (isf32=0) or fp32 (isf32=1)
__device__ __forceinline__ float load_in(const void* p, size_t i, int isf32) {
    return isf32 ? ((const float*)p)[i] : bf2f(((const u16*)p)[i]);
}

// ---------------- dtype probe: bf16-packed vs fp32 words --------------------------
__global__ void probe_kernel(const unsigned int* __restrict__ x, int* __restrict__ flag)
{
    int cnt = 0;
    for (int i = threadIdx.x; i < 256; i += 64) {
        unsigned int w = x[i];
        float v = __uint_as_float((w & 0xFFFFu) << 16);
        float a = fabsf(v);
        if (a >= 6.1e-5f && a <= 64.f) cnt++;
    }
    #pragma unroll
    for (int off = 32; off >= 1; off >>= 1) cnt += __shfl_xor(cnt, off, 64);
    if (threadIdx.x == 0) *flag = (cnt < 128) ? 1 : 0;   // 1 => inputs are fp32
}

// ---------------- GEMM1: h = relu(x @ W1 + b1); rn = 1/max(||h_row||, eps) --------
__global__ __launch_bounds__(256) void gemm1_mfma(
    const void* __restrict__ x, const void* __restrict__ W1, const void* __restrict__ b1,
    float* __restrict__ h, float* __restrict__ rn, int ngroups, int N,
    const int* __restrict__ flagp)
{
    const int isf32 = *flagp;
    const int lane = threadIdx.x & 63;
    const int m    = lane & 15;      // B col / D col
    const int quad = lane >> 4;
    const int wid  = blockIdx.x * 4 + (threadIdx.x >> 6);
    const int nw   = gridDim.x * 4;

    // B-frag for tile kb: lane holds B[k=kb*32+quad*8+j][n=m]  (j=0..7)
    short8 bfrag[16];
    #pragma unroll
    for (int kb = 0; kb < 16; ++kb)
        #pragma unroll
        for (int j = 0; j < 8; ++j) {
            size_t idx = (size_t)(kb*32 + quad*8 + j)*HID + m;
            bfrag[kb][j] = isf32 ? (short)f2bf_rne(((const float*)W1)[idx])
                                 : (short)((const u16*)W1)[idx];
        }
    const float bias = load_in(b1, m, isf32);

    for (int g = wid; g < ngroups; g += nw) {
        // clamp row for OOB-safety when N % 16 != 0 (stores are guarded below)
        size_t row = (size_t)g*16 + m;
        if (row >= (size_t)N) row = N - 1;
        f32x4 acc = {0.f, 0.f, 0.f, 0.f};
        if (isf32) {
            // vectorized: each lane owns 32B contiguous per K-block -> 2x float4
            const float* xb = (const float*)x + row*FIN + quad*8;
            #pragma unroll
            for (int kb = 0; kb < 16; ++kb) {
                f32x4 v0 = *(const f32x4*)(xb + kb*32);
                f32x4 v1 = *(const f32x4*)(xb + kb*32 + 4);
                short8 a;
                a[0] = (short)f2bf_rne(v0[0]); a[1] = (short)f2bf_rne(v0[1]);
                a[2] = (short)f2bf_rne(v0[2]); a[3] = (short)f2bf_rne(v0[3]);
                a[4] = (short)f2bf_rne(v1[0]); a[5] = (short)f2bf_rne(v1[1]);
                a[6] = (short)f2bf_rne(v1[2]); a[7] = (short)f2bf_rne(v1[3]);
                acc = __builtin_amdgcn_mfma_f32_16x16x32_bf16(a, bfrag[kb], acc, 0, 0, 0);
            }
        } else {
            const u16* xb = (const u16*)x + row*FIN + quad*8;
            #pragma unroll
            for (int kb = 0; kb < 16; ++kb) {
                short8 a = *(const short8*)(xb + kb*32);
                acc = __builtin_amdgcn_mfma_f32_16x16x32_bf16(a, bfrag[kb], acc, 0, 0, 0);
            }
        }
        // D: row = quad*4+i, col = m   [verified layout, m89/m91]
        #pragma unroll
        for (int i = 0; i < 4; ++i) {
            int r = quad*4 + i;
            float v = fmaxf(acc[i] + bias, 0.f);
            size_t orow = (size_t)g*16 + r;
            if (orow < (size_t)N) h[orow*HID + m] = v;
            float ss = v*v;
            ss += __shfl_xor(ss, 1, 64);
            ss += __shfl_xor(ss, 2, 64);
            ss += __shfl_xor(ss, 4, 64);
            ss += __shfl_xor(ss, 8, 64);
            if (m == 0 && orow < (size_t)N) rn[orow] = 1.0f / fmaxf(sqrtf(ss), 1e-12f);
        }
    }
}

// ---------------- CSR build (grouped by dst) --------------------------------------
// Partition path (no contended global atomics):
//   count (100K-addr atomics) -> bucket_sum -> scan(NB) -> row_start (per-bucket
//   wave scan; deterministic, monotonic) -> scatter_part (LDS-aggregated; one
//   global atomic per block*bucket) -> bucket_fill (LDS cursors, L2-window scatter)
__global__ __launch_bounds__(256) void count_kernel(
    const int* __restrict__ dst, int* __restrict__ counts, int E)
{
    int e = blockIdx.x * 256 + threadIdx.x;
    if (e < E) atomicAdd(&counts[dst[e]], 1);
}

__global__ __launch_bounds__(256) void bucket_sum_kernel(
    const int* __restrict__ counts, int* __restrict__ bcnt, int N, int NB)
{
    int b = blockIdx.x * 256 + threadIdx.x;
    if (b < NB) {
        int n0 = b << 7;
        int ne = min(n0 + 128, N);
        int s = 0;
        for (int n = n0; n < ne; ++n) s += counts[n];
        bcnt[b] = s;
    }
}

// single-block exclusive scan with carry (handles arbitrary n in 1024-tiles)
__global__ __launch_bounds__(1024) void scan_kernel(
    const int* __restrict__ in, int* __restrict__ out, int n)
{
    __shared__ int buf[1024];
    __shared__ int carry;
    int t = threadIdx.x;
    if (t == 0) carry = 0;
    __syncthreads();
    for (int base = 0; base < n; base += 1024) {
        int v = (base + t < n) ? in[base + t] : 0;
        buf[t] = v;
        __syncthreads();
        for (int d = 1; d < 1024; d <<= 1) {
            int x = (t >= d) ? buf[t - d] : 0;
            __syncthreads();
            buf[t] += x;
            __syncthreads();
        }
        if (base + t < n) out[base + t] = carry + buf[t] - v;
        __syncthreads();
        if (t == 0) carry += buf[1023];
        __syncthreads();
    }
}

// one wave per bucket: exclusive scan of 128 counts (2 nodes/lane) + bucket base
__global__ __launch_bounds__(256) void row_start_kernel(
    const int* __restrict__ counts, const int* __restrict__ bbase,
    int* __restrict__ row_start, int N, int NB)
{
    int b = blockIdx.x * 4 + (threadIdx.x >> 6);
    if (b >= NB) return;
    int lane = threadIdx.x & 63;
    int n0 = b << 7;
    int na = n0 + 2 * lane;
    int nb2 = na + 1;
    int c0 = (na  < N) ? counts[na]  : 0;
    int c1 = (nb2 < N) ? counts[nb2] : 0;
    int tp = c0 + c1;
    int s = tp;
    #pragma unroll
    for (int d = 1; d <= 32; d <<= 1) {
        int t = __shfl_up(s, d, 64);
        if (lane >= d) s += t;
    }
    int excl = s - tp;
    int base = bbase[b];
    if (na  < N) row_start[na]  = base + excl;
    if (nb2 < N) row_start[nb2] = base + excl + c0;
}

// LDS-aggregated partition: per-block bucket histogram -> one global atomic per
// (block,bucket) to reserve a sub-range -> LDS re-rank -> contiguous-run writes
__global__ __launch_bounds__(256) void scatter_part_kernel(
    const int* __restrict__ src, const int* __restrict__ dst,
    const int* __restrict__ bbase, int* __restrict__ bcur,
    int* __restrict__ pairs, int E, int NB)
{
    __shared__ int hist[MAXNB];
    __shared__ int base[MAXNB];
    int t = threadIdx.x;
    for (int i = t; i < NB; i += 256) hist[i] = 0;
    __syncthreads();
    int chunk = (E + gridDim.x - 1) / gridDim.x;
    int beg = blockIdx.x * chunk;
    int end = min(E, beg + chunk);
    for (int i = beg + t; i < end; i += 256)
        atomicAdd(&hist[dst[i] >> 7], 1);
    __syncthreads();
    for (int i = t; i < NB; i += 256) {
        int h = hist[i];
        base[i] = h ? (bbase[i] + atomicAdd(&bcur[i], h)) : 0;
        hist[i] = 0;
    }
    __syncthreads();
    for (int i = beg + t; i < end; i += 256) {
        int d = dst[i], s = src[i];
        int b = d >> 7;
        int r = atomicAdd(&hist[b], 1);
        // pack: local dst (7b) in [31:24], src (24b) in [23:0]; requires N <= 2^24
        pairs[base[b] + r] = ((d & 127) << 24) | s;
    }
}

__global__ __launch_bounds__(256) void bucket_fill_kernel(
    const int* __restrict__ pairs, const int* __restrict__ bbase,
    const int* __restrict__ bcnt, const int* __restrict__ row_start,
    int* __restrict__ csr, int N)
{
    int b = blockIdx.x;
    int n0 = b << 7;
    __shared__ int lrs[128];
    __shared__ int lcur[128];
    int t = threadIdx.x;
    if (t < 128) {
        lcur[t] = 0;
        int n = n0 + t;
        lrs[t] = (n < N) ? row_start[n] : 0;
    }
    __syncthreads();
    int base = bbase[b];
    int cnt  = bcnt[b];
    for (int i = t; i < cnt; i += 256) {
        int w = pairs[base + i];
        int s = w & 0xFFFFFF;
        int local = ((unsigned)w) >> 24;
        int p = atomicAdd(&lcur[local], 1);
        csr[lrs[local] + p] = s;
    }
}

// ---- legacy fallback (round-0 behavior) ----
__global__ __launch_bounds__(256) void alloc_kernel(
    const int* __restrict__ counts, int* __restrict__ row_start,
    int* __restrict__ gcur, int N)
{
    int n = blockIdx.x * 256 + threadIdx.x;
    int lane = threadIdx.x & 63;
    int cnt = (n < N) ? counts[n] : 0;
    int s = cnt;
    #pragma unroll
    for (int d = 1; d <= 32; d <<= 1) {
        int t = __shfl_up(s, d, 64);
        if (lane >= d) s += t;
    }
    int total = __shfl(s, 63, 64);
    int base = 0;
    if (lane == 0) base = atomicAdd(gcur, total);
    base = __shfl(base, 0, 64);
    if (n < N) row_start[n] = base + s - cnt;
}

__global__ __launch_bounds__(256) void fill_kernel(
    const int* __restrict__ src, const int* __restrict__ dst,
    const int* __restrict__ row_start, int* __restrict__ cursor,
    int* __restrict__ csr, int E)
{
    int e = blockIdx.x * 256 + threadIdx.x;
    if (e < E) {
        int d = dst[e];
        int p = atomicAdd(&cursor[d], 1);
        csr[row_start[d] + p] = src[e];
    }
}

// ---------------- AGNN propagation: one wave per dst node -------------------------
// Softmax via CONSTANT shift M = |beta| (alpha in [-|beta|,|beta|] by C-S):
// shift-invariant => identical to reference, branch-free, exp args <= 0.
__global__ __launch_bounds__(256) void prop_kernel(
    const float* __restrict__ f, const float* __restrict__ rn,
    const int* __restrict__ row_start, const int* __restrict__ counts,
    const int* __restrict__ csr, const void* __restrict__ beta_ptr, int use_beta,
    float* __restrict__ out, float* __restrict__ rn_out, int N,
    const int* __restrict__ flagp)
{
    int wid = blockIdx.x * 4 + (threadIdx.x >> 6);
    if (wid >= N) return;
    const int isf32 = *flagp;
    const int lane = threadIdx.x & 63;
    const int c = lane & 15;
    const int g = lane >> 4;
    const int n = wid;

    const float beta = use_beta ? load_in(beta_ptr, 0, isf32) : 1.0f;
    const float M = fabsf(beta);
    const float fn_c = f[(size_t)n*HID + c];
    const float rn_n = rn[n];
    const int base = row_start[n];
    const int deg  = counts[n];

    float s = 0.f, acc = 0.f;
    for (int j = g; j < deg + 1; j += 4) {
        int idx = base + ((j < deg) ? j : 0);   // address always in-bounds
        int v = csr[idx];
        int src = (j < deg) ? v : n;            // virtual self-loop at j==deg
        float fs = f[(size_t)src*HID + c];
        float rs = rn[src];
        float p = fs * fn_c;                    // group-wide dot (16 lanes)
        p += __shfl_xor(p, 1, 64);
        p += __shfl_xor(p, 2, 64);
        p += __shfl_xor(p, 4, 64);
        p += __shfl_xor(p, 8, 64);
        float alpha = beta * p * rs * rn_n;     // in [-|beta|, |beta|]
        float t = __expf(alpha - M);            // in (0, 1]
        s   += t;
        acc += t * fs;
    }
    #pragma unroll
    for (int off = 16; off <= 32; off <<= 1) {  // merge the 4 groups
        s   += __shfl_xor(s, off, 64);
        acc += __shfl_xor(acc, off, 64);
    }
    float o = acc / s;
    if (lane < HID) out[(size_t)n*HID + lane] = o;
    float p2 = o * o;
    p2 += __shfl_xor(p2, 1, 64);
    p2 += __shfl_xor(p2, 2, 64);
    p2 += __shfl_xor(p2, 4, 64);
    p2 += __shfl_xor(p2, 8, 64);
    if (lane == 0) rn_out[n] = 1.0f / fmaxf(sqrtf(p2), 1e-12f);
}

// ---------------- classifier + log_softmax ----------------------------------------
__global__ __launch_bounds__(256) void classify_kernel(
    const float* __restrict__ h2, const void* __restrict__ W2,
    const void* __restrict__ b2, void* __restrict__ out, int N,
    const int* __restrict__ flagp)
{
    const int isf32 = *flagp;
    __shared__ float w2s[HID * NCLS];
    __shared__ float b2s[NCLS];
    for (int i = threadIdx.x; i < HID * NCLS; i += 256) w2s[i] = load_in(W2, i, isf32);
    if (threadIdx.x < NCLS) b2s[threadIdx.x] = load_in(b2, threadIdx.x, isf32);
    __syncthreads();

    int wid = blockIdx.x * 4 + (threadIdx.x >> 6);
    if (wid >= N) return;
    const int lane = threadIdx.x & 63;
    const int n = wid;

    float acc = -3.0e38f;
    if (lane < NCLS) {
        acc = b2s[lane];
        #pragma unroll
        for (int k = 0; k < HID; ++k)
            acc += h2[(size_t)n*HID + k] * w2s[k*NCLS + lane];
    }
    float mx = acc;
    #pragma unroll
    for (int off = 32; off >= 1; off >>= 1)
        mx = fmaxf(mx, __shfl_xor(mx, off, 64));
    float e = (lane < NCLS) ? __expf(acc - mx) : 0.f;
    float sum = e;
    #pragma unroll
    for (int off = 32; off >= 1; off >>= 1)
        sum += __shfl_xor(sum, off, 64);
    if (lane < NCLS) {
        float res = acc - mx - __logf(sum);
        if (!(res == res) || fabsf(res) > 1e30f) res = 0.f;
        size_t oi = (size_t)n*NCLS + lane;
        if (isf32) ((float*)out)[oi] = res;
        else       ((u16*)out)[oi]  = f2bf_rne(res);
    }
}

extern "C" void kernel_launch(void* const* d_in, const int* in_sizes, int n_in,
                              void* d_out, int out_size, void* d_ws, size_t ws_size,
                              hipStream_t stream)
{
    const void* x     = d_in[0];
    const int*  ei    = (const int*)d_in[1];
    const void* W1    = d_in[2];
    const void* b1    = d_in[3];
    const void* W2    = d_in[4];
    const void* b2    = d_in[5];
    const void* beta2 = d_in[6];

    const int N = in_sizes[0] / FIN;
    const int E = in_sizes[1] / 2;
    const int NB = (N + 127) >> 7;           // 128-node buckets
    const int* srcv = ei;
    const int* dstv = ei + E;

    char* ws = (char*)d_ws;
    size_t off = 0;
    auto take = [&](size_t bytes) -> char* {
        char* p = ws + off;
        off += (bytes + 255) & ~(size_t)255;
        return p;
    };
    // ---- minimal layout first ----
    float* h0        = (float*)take((size_t)N * HID * 4);
    float* rn0       = (float*)take((size_t)N * 4);
    // ---- zeroed range start ----
    int*   counts    = (int*)take((size_t)N * 4);
    int*   cursor    = (int*)take((size_t)N * 4);   // legacy path only
    int*   bcur      = (int*)take((size_t)NB * 4);
    int*   gcur      = (int*)take(256);             // legacy path only
    // ---- zeroed range end ----
    int*   row_start = (int*)take((size_t)N * 4);
    int*   bcnt      = (int*)take((size_t)NB * 4);
    int*   bbase     = (int*)take((size_t)NB * 4);
    int*   csr       = (int*)take((size_t)(E + 64) * 4);
    int*   flag      = (int*)take(256);                   // NOT in memset range
    // ---- optional partition buffer: only used if it fits ws_size ----
    int*   pairs     = (int*)take((size_t)(E + 64) * 4);
    const int use_bucket = (off <= ws_size && NB <= MAXNB && N <= (1 << 24)) ? 1 : 0;

    // h1/rn1 live in d_out (dead before classify overwrites it); worst-case
    // d_out is bf16 -> 8MB >= 6.8MB needed.
    float* h1  = (float*)d_out;
    float* rn1 = (float*)((char*)d_out + (size_t)N * HID * 4);
    float* h2  = h0;   // h0 dead after prop1
    float* rn2 = rn0;  // sink for prop2's rnorm (unused)

    size_t zbytes = (size_t)((char*)gcur - (char*)counts) + 256;
    hipMemsetAsync(counts, 0, zbytes, stream);

    probe_kernel<<<1, 64, 0, stream>>>((const unsigned int*)x, flag);

    const int ngroups = (N + 15) / 16;
    gemm1_mfma<<<782, 256, 0, stream>>>(x, W1, b1, h0, rn0, ngroups, N, flag);

    int eb = (E + 255) / 256;
    int nb = (N + 255) / 256;
    int bb = (NB + 255) / 256;
    int wb = (N + 3) / 4;                       // one wave per node
    count_kernel<<<eb, 256, 0, stream>>>(dstv, counts, E);
    if (use_bucket) {
        bucket_sum_kernel<<<bb, 256, 0, stream>>>(counts, bcnt, N, NB);
        scan_kernel<<<1, 1024, 0, stream>>>(bcnt, bbase, NB);
        row_start_kernel<<<(NB + 3) / 4, 256, 0, stream>>>(counts, bbase, row_start, N, NB);
        scatter_part_kernel<<<256, 256, 0, stream>>>(srcv, dstv, bbase, bcur, pairs, E, NB);
        bucket_fill_kernel<<<NB, 256, 0, stream>>>(pairs, bbase, bcnt, row_start, csr, N);
    } else {
        alloc_kernel<<<nb, 256, 0, stream>>>(counts, row_start, gcur, N);
        fill_kernel<<<eb, 256, 0, stream>>>(srcv, dstv, row_start, cursor, csr, E);
    }

    prop_kernel<<<wb, 256, 0, stream>>>(h0, rn0, row_start, counts, csr,
                                        b1, 0, h1, rn1, N, flag);
    prop_kernel<<<wb, 256, 0, stream>>>(h1, rn1, row_start, counts, csr,
                                        beta2, 1, h2, rn2, N, flag);

    classify_kernel<<<wb, 256, 0, stream>>>(h2, W2, b2, d_out, N, flag);
}

// Round 4
// 685.700 us; speedup vs baseline: 3.3390x; 1.2598x over previous
//
#include <hip/hip_runtime.h>
#include <hip/hip_bf16.h>

#define FIN 512
#define HID 16
#define NCLS 40
#define MAXNB 1024   // max buckets supported by LDS partition path
#define NBLK 256     // scatter/hist grid (must match between hist2d & scatter)

typedef unsigned short u16;
typedef __attribute__((ext_vector_type(8))) short short8;
typedef __attribute__((ext_vector_type(4))) float f32x4;

__device__ __forceinline__ float bf2f(u16 u) {
    return __uint_as_float(((unsigned int)u) << 16);
}
__device__ __forceinline__ u16 f2bf_rne(float f) {
    unsigned int u = __float_as_uint(f);
    unsigned int r = u + 0x7FFFu + ((u >> 16) & 1u);
    return (u16)(r >> 16);
}
// load element i of a float input that is either bf16 (isf32=0) or fp32 (isf32=1)
__device__ __forceinline__ float load_in(const void* p, size_t i, int isf32) {
    return isf32 ? ((const float*)p)[i] : bf2f(((const u16*)p)[i]);
}

// ---------------- dtype probe: bf16-packed vs fp32 words --------------------------
__global__ void probe_kernel(const unsigned int* __restrict__ x, int* __restrict__ flag)
{
    int cnt = 0;
    for (int i = threadIdx.x; i < 256; i += 64) {
        unsigned int w = x[i];
        float v = __uint_as_float((w & 0xFFFFu) << 16);
        float a = fabsf(v);
        if (a >= 6.1e-5f && a <= 64.f) cnt++;
    }
    #pragma unroll
    for (int off = 32; off >= 1; off >>= 1) cnt += __shfl_xor(cnt, off, 64);
    if (threadIdx.x == 0) *flag = (cnt < 128) ? 1 : 0;   // 1 => inputs are fp32
}

// ---------------- GEMM1: h = relu(x @ W1 + b1); rn = 1/max(||h_row||, eps) --------
// W1 fragments live in LDS (shared by all 4 waves): frees 64 VGPRs so the
// compiler can keep many independent x-loads in flight (the round-3 kernel was
// latency-bound: VGPR=76 with 64 pinned by bfrag => vmcnt drain every K-step).
__global__ __launch_bounds__(256) void gemm1_mfma(
    const void* __restrict__ x, const void* __restrict__ W1, const void* __restrict__ b1,
    float* __restrict__ h, float* __restrict__ rn, int ngroups, int N,
    const int* __restrict__ flagp)
{
    const int isf32 = *flagp;
    __shared__ u16 w1s[8192];    // [kb][lane][j] bf16 fragments, 16 KB
    __shared__ float b1s[HID];
    const int lane = threadIdx.x & 63;
    const int m    = lane & 15;      // B col / D col
    const int quad = lane >> 4;

    // cooperative stage: w1s[kb*512 + ln*8 + j] = B[k=kb*32+(ln>>4)*8+j][ln&15]
    for (int i = threadIdx.x; i < 8192; i += 256) {
        int kb = i >> 9, rem = i & 511, ln = rem >> 3, j = rem & 7;
        int k = kb*32 + (ln >> 4)*8 + j;
        w1s[i] = f2bf_rne(load_in(W1, (size_t)k*HID + (ln & 15), isf32));
    }
    if (threadIdx.x < HID) b1s[threadIdx.x] = load_in(b1, threadIdx.x, isf32);
    __syncthreads();

    const int wid = blockIdx.x * 4 + (threadIdx.x >> 6);
    const int nw  = gridDim.x * 4;
    const float bias = b1s[m];

    for (int g = wid; g < ngroups; g += nw) {
        // clamp row for OOB-safety when N % 16 != 0 (stores are guarded below)
        size_t row = (size_t)g*16 + m;
        if (row >= (size_t)N) row = N - 1;
        f32x4 acc = {0.f, 0.f, 0.f, 0.f};
        if (isf32) {
            const float* xb = (const float*)x + row*FIN + quad*8;
            #pragma unroll
            for (int kb = 0; kb < 16; ++kb) {
                f32x4 v0 = *(const f32x4*)(xb + kb*32);
                f32x4 v1 = *(const f32x4*)(xb + kb*32 + 4);
                short8 a;
                a[0] = (short)f2bf_rne(v0[0]); a[1] = (short)f2bf_rne(v0[1]);
                a[2] = (short)f2bf_rne(v0[2]); a[3] = (short)f2bf_rne(v0[3]);
                a[4] = (short)f2bf_rne(v1[0]); a[5] = (short)f2bf_rne(v1[1]);
                a[6] = (short)f2bf_rne(v1[2]); a[7] = (short)f2bf_rne(v1[3]);
                short8 bf = *(const short8*)&w1s[kb*512 + lane*8];
                acc = __builtin_amdgcn_mfma_f32_16x16x32_bf16(a, bf, acc, 0, 0, 0);
            }
        } else {
            const u16* xb = (const u16*)x + row*FIN + quad*8;
            #pragma unroll
            for (int kb = 0; kb < 16; ++kb) {
                short8 a = *(const short8*)(xb + kb*32);
                short8 bf = *(const short8*)&w1s[kb*512 + lane*8];
                acc = __builtin_amdgcn_mfma_f32_16x16x32_bf16(a, bf, acc, 0, 0, 0);
            }
        }
        // D: row = quad*4+i, col = m   [verified layout, m89/m91]
        #pragma unroll
        for (int i = 0; i < 4; ++i) {
            int r = quad*4 + i;
            float v = fmaxf(acc[i] + bias, 0.f);
            size_t orow = (size_t)g*16 + r;
            if (orow < (size_t)N) h[orow*HID + m] = v;
            float ss = v*v;
            ss += __shfl_xor(ss, 1, 64);
            ss += __shfl_xor(ss, 2, 64);
            ss += __shfl_xor(ss, 4, 64);
            ss += __shfl_xor(ss, 8, 64);
            if (m == 0 && orow < (size_t)N) rn[orow] = 1.0f / fmaxf(sqrtf(ss), 1e-12f);
        }
    }
}

// ---------------- CSR build (grouped by dst) — zero global atomics ----------------
// hist2d: per-block LDS bucket histogram -> blkhist[blk][NB]
// scanB:  per-bucket exclusive scan over blocks (in-place) + bcnt
// scan:   exclusive scan bcnt -> bbase
// scatter: pairs[bbase[b]+blkoff[blk][b]+rank] = (local_dst<<24 | src)
// bucket_fill: LDS hist -> counts/row_start; LDS cursors -> csr (L2-window)
__global__ __launch_bounds__(256) void hist2d_kernel(
    const int* __restrict__ dst, int* __restrict__ blkhist, int E, int NB)
{
    __shared__ int hist[MAXNB];
    int t = threadIdx.x;
    for (int i = t; i < NB; i += 256) hist[i] = 0;
    __syncthreads();
    int chunk = (E + gridDim.x - 1) / gridDim.x;
    int beg = blockIdx.x * chunk;
    int end = min(E, beg + chunk);
    for (int i = beg + t; i < end; i += 256)
        atomicAdd(&hist[dst[i] >> 7], 1);
    __syncthreads();
    for (int i = t; i < NB; i += 256)
        blkhist[blockIdx.x * NB + i] = hist[i];
}

__global__ __launch_bounds__(256) void scanB_kernel(
    int* __restrict__ blkhist, int* __restrict__ bcnt, int NB)
{
    int b = blockIdx.x * 4 + (threadIdx.x >> 6);
    if (b >= NB) return;
    int lane = threadIdx.x & 63;
    int run = 0;
    for (int i0 = 0; i0 < NBLK; i0 += 64) {
        int idx = (i0 + lane) * NB + b;
        int v = blkhist[idx];
        int s = v;
        #pragma unroll
        for (int d = 1; d <= 32; d <<= 1) {
            int u = __shfl_up(s, d, 64);
            if (lane >= d) s += u;
        }
        blkhist[idx] = run + s - v;      // exclusive offset of this block in b
        run += __shfl(s, 63, 64);
    }
    if (lane == 0) bcnt[b] = run;
}

// single-block exclusive scan with carry (handles arbitrary n in 1024-tiles)
__global__ __launch_bounds__(1024) void scan_kernel(
    const int* __restrict__ in, int* __restrict__ out, int n)
{
    __shared__ int buf[1024];
    __shared__ int carry;
    int t = threadIdx.x;
    if (t == 0) carry = 0;
    __syncthreads();
    for (int base = 0; base < n; base += 1024) {
        int v = (base + t < n) ? in[base + t] : 0;
        buf[t] = v;
        __syncthreads();
        for (int d = 1; d < 1024; d <<= 1) {
            int x = (t >= d) ? buf[t - d] : 0;
            __syncthreads();
            buf[t] += x;
            __syncthreads();
        }
        if (base + t < n) out[base + t] = carry + buf[t] - v;
        __syncthreads();
        if (t == 0) carry += buf[1023];
        __syncthreads();
    }
}

__global__ __launch_bounds__(256) void scatter_part_kernel(
    const int* __restrict__ src, const int* __restrict__ dst,
    const int* __restrict__ bbase, const int* __restrict__ blkhist,
    int* __restrict__ pairs, int E, int NB)
{
    __shared__ int base[MAXNB];
    __shared__ int cur[MAXNB];
    int t = threadIdx.x;
    for (int i = t; i < NB; i += 256) {
        base[i] = bbase[i] + blkhist[blockIdx.x * NB + i];
        cur[i] = 0;
    }
    __syncthreads();
    int chunk = (E + gridDim.x - 1) / gridDim.x;   // must match hist2d
    int beg = blockIdx.x * chunk;
    int end = min(E, beg + chunk);
    for (int i = beg + t; i < end; i += 256) {
        int d = dst[i], s = src[i];
        int b = d >> 7;
        int r = atomicAdd(&cur[b], 1);
        // pack: local dst (7b) in [31:24], src (24b) in [23:0]; requires N <= 2^24
        pairs[base[b] + r] = ((d & 127) << 24) | s;
    }
}

__global__ __launch_bounds__(256) void bucket_fill_kernel(
    const int* __restrict__ pairs, const int* __restrict__ bbase,
    const int* __restrict__ bcnt, int* __restrict__ row_start,
    int* __restrict__ counts, int* __restrict__ csr, int N)
{
    int b = blockIdx.x, n0 = b << 7;
    __shared__ int lhist[128], loff[128], lcur[128];
    int t = threadIdx.x;
    if (t < 128) { lhist[t] = 0; lcur[t] = 0; }
    __syncthreads();
    int base = bbase[b], cnt = bcnt[b];
    for (int i = t; i < cnt; i += 256)
        atomicAdd(&lhist[((unsigned)pairs[base + i]) >> 24], 1);
    __syncthreads();
    if (t < 64) {   // wave 0: scan 128 counts (2/lane), emit counts/row_start
        int c0 = lhist[2*t], c1 = lhist[2*t + 1];
        int tp = c0 + c1, s = tp;
        #pragma unroll
        for (int d = 1; d <= 32; d <<= 1) {
            int u = __shfl_up(s, d, 64);
            if (t >= d) s += u;
        }
        int excl = s - tp;
        loff[2*t] = excl; loff[2*t + 1] = excl + c0;
        int na = n0 + 2*t, nb2 = na + 1;
        if (na < N)  { row_start[na]  = base + excl;      counts[na]  = c0; }
        if (nb2 < N) { row_start[nb2] = base + excl + c0; counts[nb2] = c1; }
    }
    __syncthreads();
    for (int i = t; i < cnt; i += 256) {
        int w = pairs[base + i];
        int s = w & 0xFFFFFF, l = ((unsigned)w) >> 24;
        int p = atomicAdd(&lcur[l], 1);
        csr[base + loff[l] + p] = s;
    }
}

// ---- legacy fallback (round-0 behavior) ----
__global__ __launch_bounds__(256) void count_kernel(
    const int* __restrict__ dst, int* __restrict__ counts, int E)
{
    int e = blockIdx.x * 256 + threadIdx.x;
    if (e < E) atomicAdd(&counts[dst[e]], 1);
}

__global__ __launch_bounds__(256) void alloc_kernel(
    const int* __restrict__ counts, int* __restrict__ row_start,
    int* __restrict__ gcur, int N)
{
    int n = blockIdx.x * 256 + threadIdx.x;
    int lane = threadIdx.x & 63;
    int cnt = (n < N) ? counts[n] : 0;
    int s = cnt;
    #pragma unroll
    for (int d = 1; d <= 32; d <<= 1) {
        int t = __shfl_up(s, d, 64);
        if (lane >= d) s += t;
    }
    int total = __shfl(s, 63, 64);
    int base = 0;
    if (lane == 0) base = atomicAdd(gcur, total);
    base = __shfl(base, 0, 64);
    if (n < N) row_start[n] = base + s - cnt;
}

__global__ __launch_bounds__(256) void fill_kernel(
    const int* __restrict__ src, const int* __restrict__ dst,
    const int* __restrict__ row_start, int* __restrict__ cursor,
    int* __restrict__ csr, int E)
{
    int e = blockIdx.x * 256 + threadIdx.x;
    if (e < E) {
        int d = dst[e];
        int p = atomicAdd(&cursor[d], 1);
        csr[row_start[d] + p] = src[e];
    }
}

// ---------------- AGNN propagation: one wave per dst node -------------------------
// Softmax via CONSTANT shift M = |beta| (alpha in [-|beta|,|beta|] by C-S):
// shift-invariant => identical to reference, branch-free, exp args <= 0.
__global__ __launch_bounds__(256) void prop_kernel(
    const float* __restrict__ f, const float* __restrict__ rn,
    const int* __restrict__ row_start, const int* __restrict__ counts,
    const int* __restrict__ csr, const void* __restrict__ beta_ptr, int use_beta,
    float* __restrict__ out, float* __restrict__ rn_out, int N,
    const int* __restrict__ flagp)
{
    int wid = blockIdx.x * 4 + (threadIdx.x >> 6);
    if (wid >= N) return;
    const int isf32 = *flagp;
    const int lane = threadIdx.x & 63;
    const int c = lane & 15;
    const int g = lane >> 4;
    const int n = wid;

    const float beta = use_beta ? load_in(beta_ptr, 0, isf32) : 1.0f;
    const float M = fabsf(beta);
    const float fn_c = f[(size_t)n*HID + c];
    const float rn_n = rn[n];
    const int base = row_start[n];
    const int deg  = counts[n];

    float s = 0.f, acc = 0.f;
    for (int j = g; j < deg + 1; j += 4) {
        int idx = base + ((j < deg) ? j : 0);   // address always in-bounds
        int v = csr[idx];
        int src = (j < deg) ? v : n;            // virtual self-loop at j==deg
        float fs = f[(size_t)src*HID + c];
        float rs = rn[src];
        float p = fs * fn_c;                    // group-wide dot (16 lanes)
        p += __shfl_xor(p, 1, 64);
        p += __shfl_xor(p, 2, 64);
        p += __shfl_xor(p, 4, 64);
        p += __shfl_xor(p, 8, 64);
        float alpha = beta * p * rs * rn_n;     // in [-|beta|, |beta|]
        float t = __expf(alpha - M);            // in (0, 1]
        s   += t;
        acc += t * fs;
    }
    #pragma unroll
    for (int off = 16; off <= 32; off <<= 1) {  // merge the 4 groups
        s   += __shfl_xor(s, off, 64);
        acc += __shfl_xor(acc, off, 64);
    }
    float o = acc / s;
    if (lane < HID) out[(size_t)n*HID + lane] = o;
    float p2 = o * o;
    p2 += __shfl_xor(p2, 1, 64);
    p2 += __shfl_xor(p2, 2, 64);
    p2 += __shfl_xor(p2, 4, 64);
    p2 += __shfl_xor(p2, 8, 64);
    if (lane == 0) rn_out[n] = 1.0f / fmaxf(sqrtf(p2), 1e-12f);
}

// ---------------- classifier + log_softmax ----------------------------------------
__global__ __launch_bounds__(256) void classify_kernel(
    const float* __restrict__ h2, const void* __restrict__ W2,
    const void* __restrict__ b2, void* __restrict__ out, int N,
    const int* __restrict__ flagp)
{
    const int isf32 = *flagp;
    __shared__ float w2s[HID * NCLS];
    __shared__ float b2s[NCLS];
    for (int i = threadIdx.x; i < HID * NCLS; i += 256) w2s[i] = load_in(W2, i, isf32);
    if (threadIdx.x < NCLS) b2s[threadIdx.x] = load_in(b2, threadIdx.x, isf32);
    __syncthreads();

    int wid = blockIdx.x * 4 + (threadIdx.x >> 6);
    if (wid >= N) return;
    const int lane = threadIdx.x & 63;
    const int n = wid;

    float acc = -3.0e38f;
    if (lane < NCLS) {
        acc = b2s[lane];
        #pragma unroll
        for (int k = 0; k < HID; ++k)
            acc += h2[(size_t)n*HID + k] * w2s[k*NCLS + lane];
    }
    float mx = acc;
    #pragma unroll
    for (int off = 32; off >= 1; off >>= 1)
        mx = fmaxf(mx, __shfl_xor(mx, off, 64));
    float e = (lane < NCLS) ? __expf(acc - mx) : 0.f;
    float sum = e;
    #pragma unroll
    for (int off = 32; off >= 1; off >>= 1)
        sum += __shfl_xor(sum, off, 64);
    if (lane < NCLS) {
        float res = acc - mx - __logf(sum);
        if (!(res == res) || fabsf(res) > 1e30f) res = 0.f;
        size_t oi = (size_t)n*NCLS + lane;
        if (isf32) ((float*)out)[oi] = res;
        else       ((u16*)out)[oi]  = f2bf_rne(res);
    }
}

extern "C" void kernel_launch(void* const* d_in, const int* in_sizes, int n_in,
                              void* d_out, int out_size, void* d_ws, size_t ws_size,
                              hipStream_t stream)
{
    const void* x     = d_in[0];
    const int*  ei    = (const int*)d_in[1];
    const void* W1    = d_in[2];
    const void* b1    = d_in[3];
    const void* W2    = d_in[4];
    const void* b2    = d_in[5];
    const void* beta2 = d_in[6];

    const int N = in_sizes[0] / FIN;
    const int E = in_sizes[1] / 2;
    const int NB = (N + 127) >> 7;           // 128-node buckets
    const int* srcv = ei;
    const int* dstv = ei + E;

    char* ws = (char*)d_ws;
    size_t off = 0;
    auto take = [&](size_t bytes) -> char* {
        char* p = ws + off;
        off += (bytes + 255) & ~(size_t)255;
        return p;
    };
    // ---- minimal layout first ----
    float* h0        = (float*)take((size_t)N * HID * 4);
    float* rn0       = (float*)take((size_t)N * 4);
    // ---- zeroed range start (legacy path needs these zeroed) ----
    int*   counts    = (int*)take((size_t)N * 4);
    int*   cursor    = (int*)take((size_t)N * 4);
    int*   gcur      = (int*)take(256);
    // ---- zeroed range end ----
    int*   row_start = (int*)take((size_t)N * 4);
    int*   bcnt      = (int*)take((size_t)NB * 4);
    int*   bbase     = (int*)take((size_t)NB * 4);
    int*   csr       = (int*)take((size_t)(E + 64) * 4);
    int*   flag      = (int*)take(256);                   // NOT in memset range
    // ---- optional partition buffers: only used if they fit ws_size ----
    int*   pairs     = (int*)take((size_t)(E + 64) * 4);
    int*   blkhist   = (int*)take((size_t)NBLK * NB * 4);
    const int use_bucket = (off <= ws_size && NB <= MAXNB && N <= (1 << 24)) ? 1 : 0;

    // h1/rn1 live in d_out (dead before classify overwrites it); worst-case
    // d_out is bf16 -> 8MB >= 6.8MB needed.
    float* h1  = (float*)d_out;
    float* rn1 = (float*)((char*)d_out + (size_t)N * HID * 4);
    float* h2  = h0;   // h0 dead after prop1
    float* rn2 = rn0;  // sink for prop2's rnorm (unused)

    size_t zbytes = (size_t)((char*)gcur - (char*)counts) + 256;
    hipMemsetAsync(counts, 0, zbytes, stream);

    probe_kernel<<<1, 64, 0, stream>>>((const unsigned int*)x, flag);

    const int ngroups = (N + 15) / 16;
    gemm1_mfma<<<(ngroups + 3) / 4, 256, 0, stream>>>(x, W1, b1, h0, rn0, ngroups, N, flag);

    int eb = (E + 255) / 256;
    int nb = (N + 255) / 256;
    int wb = (N + 3) / 4;                       // one wave per node
    if (use_bucket) {
        hist2d_kernel<<<NBLK, 256, 0, stream>>>(dstv, blkhist, E, NB);
        scanB_kernel<<<(NB + 3) / 4, 256, 0, stream>>>(blkhist, bcnt, NB);
        scan_kernel<<<1, 1024, 0, stream>>>(bcnt, bbase, NB);
        scatter_part_kernel<<<NBLK, 256, 0, stream>>>(srcv, dstv, bbase, blkhist, pairs, E, NB);
        bucket_fill_kernel<<<NB, 256, 0, stream>>>(pairs, bbase, bcnt, row_start, counts, csr, N);
    } else {
        count_kernel<<<eb, 256, 0, stream>>>(dstv, counts, E);
        alloc_kernel<<<nb, 256, 0, stream>>>(counts, row_start, gcur, N);
        fill_kernel<<<eb, 256, 0, stream>>>(srcv, dstv, row_start, cursor, csr, E);
    }

    prop_kernel<<<wb, 256, 0, stream>>>(h0, rn0, row_start, counts, csr,
                                        b1, 0, h1, rn1, N, flag);
    prop_kernel<<<wb, 256, 0, stream>>>(h1, rn1, row_start, counts, csr,
                                        beta2, 1, h2, rn2, N, flag);

    classify_kernel<<<wb, 256, 0, stream>>>(h2, W2, b2, d_out, N, flag);
}

// Round 5
// 583.649 us; speedup vs baseline: 3.9228x; 1.1748x over previous
//
#include <hip/hip_runtime.h>
#include <hip/hip_bf16.h>

#define FIN 512
#define HID 16
#define NCLS 40
#define MAXNB 1024   // max buckets supported by LDS partition path
#define NBLK 256     // scatter/hist grid (must match between hist2d & scatter)

typedef unsigned short u16;
typedef __attribute__((ext_vector_type(8))) short short8;
typedef __attribute__((ext_vector_type(4))) float f32x4;

__device__ __forceinline__ float bf2f(u16 u) {
    return __uint_as_float(((unsigned int)u) << 16);
}
__device__ __forceinline__ u16 f2bf_rne(float f) {
    unsigned int u = __float_as_uint(f);
    unsigned int r = u + 0x7FFFu + ((u >> 16) & 1u);
    return (u16)(r >> 16);
}
// load element i of a float input that is either bf16 (isf32=0) or fp32 (isf32=1)
__device__ __forceinline__ float load_in(const void* p, size_t i, int isf32) {
    return isf32 ? ((const float*)p)[i] : bf2f(((const u16*)p)[i]);
}

// ---------------- dtype probe: bf16-packed vs fp32 words --------------------------
__global__ void probe_kernel(const unsigned int* __restrict__ x, int* __restrict__ flag)
{
    int cnt = 0;
    for (int i = threadIdx.x; i < 256; i += 64) {
        unsigned int w = x[i];
        float v = __uint_as_float((w & 0xFFFFu) << 16);
        float a = fabsf(v);
        if (a >= 6.1e-5f && a <= 64.f) cnt++;
    }
    #pragma unroll
    for (int off = 32; off >= 1; off >>= 1) cnt += __shfl_xor(cnt, off, 64);
    if (threadIdx.x == 0) *flag = (cnt < 128) ? 1 : 0;   // 1 => inputs are fp32
}

// ---------------- GEMM1: h = relu(x @ W1 + b1); rn = 1/max(||h_row||, eps) --------
// W1 fragments live in LDS (shared by all 4 waves): frees 64 VGPRs so the
// compiler can keep many independent x-loads in flight.
__global__ __launch_bounds__(256) void gemm1_mfma(
    const void* __restrict__ x, const void* __restrict__ W1, const void* __restrict__ b1,
    float* __restrict__ h, float* __restrict__ rn, int ngroups, int N,
    const int* __restrict__ flagp)
{
    const int isf32 = *flagp;
    __shared__ u16 w1s[8192];    // [kb][lane][j] bf16 fragments, 16 KB
    __shared__ float b1s[HID];
    const int lane = threadIdx.x & 63;
    const int m    = lane & 15;      // B col / D col
    const int quad = lane >> 4;

    // cooperative stage: w1s[kb*512 + ln*8 + j] = B[k=kb*32+(ln>>4)*8+j][ln&15]
    for (int i = threadIdx.x; i < 8192; i += 256) {
        int kb = i >> 9, rem = i & 511, ln = rem >> 3, j = rem & 7;
        int k = kb*32 + (ln >> 4)*8 + j;
        w1s[i] = f2bf_rne(load_in(W1, (size_t)k*HID + (ln & 15), isf32));
    }
    if (threadIdx.x < HID) b1s[threadIdx.x] = load_in(b1, threadIdx.x, isf32);
    __syncthreads();

    const int wid = blockIdx.x * 4 + (threadIdx.x >> 6);
    const int nw  = gridDim.x * 4;
    const float bias = b1s[m];

    for (int g = wid; g < ngroups; g += nw) {
        // clamp row for OOB-safety when N % 16 != 0 (stores are guarded below)
        size_t row = (size_t)g*16 + m;
        if (row >= (size_t)N) row = N - 1;
        f32x4 acc = {0.f, 0.f, 0.f, 0.f};
        if (isf32) {
            const float* xb = (const float*)x + row*FIN + quad*8;
            #pragma unroll
            for (int kb = 0; kb < 16; ++kb) {
                f32x4 v0 = *(const f32x4*)(xb + kb*32);
                f32x4 v1 = *(const f32x4*)(xb + kb*32 + 4);
                short8 a;
                a[0] = (short)f2bf_rne(v0[0]); a[1] = (short)f2bf_rne(v0[1]);
                a[2] = (short)f2bf_rne(v0[2]); a[3] = (short)f2bf_rne(v0[3]);
                a[4] = (short)f2bf_rne(v1[0]); a[5] = (short)f2bf_rne(v1[1]);
                a[6] = (short)f2bf_rne(v1[2]); a[7] = (short)f2bf_rne(v1[3]);
                short8 bf = *(const short8*)&w1s[kb*512 + lane*8];
                acc = __builtin_amdgcn_mfma_f32_16x16x32_bf16(a, bf, acc, 0, 0, 0);
            }
        } else {
            const u16* xb = (const u16*)x + row*FIN + quad*8;
            #pragma unroll
            for (int kb = 0; kb < 16; ++kb) {
                short8 a = *(const short8*)(xb + kb*32);
                short8 bf = *(const short8*)&w1s[kb*512 + lane*8];
                acc = __builtin_amdgcn_mfma_f32_16x16x32_bf16(a, bf, acc, 0, 0, 0);
            }
        }
        // D: row = quad*4+i, col = m   [verified layout, m89/m91]
        #pragma unroll
        for (int i = 0; i < 4; ++i) {
            int r = quad*4 + i;
            float v = fmaxf(acc[i] + bias, 0.f);
            size_t orow = (size_t)g*16 + r;
            if (orow < (size_t)N) h[orow*HID + m] = v;
            float ss = v*v;
            ss += __shfl_xor(ss, 1, 64);
            ss += __shfl_xor(ss, 2, 64);
            ss += __shfl_xor(ss, 4, 64);
            ss += __shfl_xor(ss, 8, 64);
            if (m == 0 && orow < (size_t)N) rn[orow] = 1.0f / fmaxf(sqrtf(ss), 1e-12f);
        }
    }
}

// ---------------- CSR build (grouped by dst) — zero global atomics ----------------
__global__ __launch_bounds__(256) void hist2d_kernel(
    const int* __restrict__ dst, int* __restrict__ blkhist, int E, int NB)
{
    __shared__ int hist[MAXNB];
    int t = threadIdx.x;
    for (int i = t; i < NB; i += 256) hist[i] = 0;
    __syncthreads();
    int chunk = (E + gridDim.x - 1) / gridDim.x;
    int beg = blockIdx.x * chunk;
    int end = min(E, beg + chunk);
    for (int i = beg + t; i < end; i += 256)
        atomicAdd(&hist[dst[i] >> 7], 1);
    __syncthreads();
    for (int i = t; i < NB; i += 256)
        blkhist[blockIdx.x * NB + i] = hist[i];
}

__global__ __launch_bounds__(256) void scanB_kernel(
    int* __restrict__ blkhist, int* __restrict__ bcnt, int NB)
{
    int b = blockIdx.x * 4 + (threadIdx.x >> 6);
    if (b >= NB) return;
    int lane = threadIdx.x & 63;
    int run = 0;
    for (int i0 = 0; i0 < NBLK; i0 += 64) {
        int idx = (i0 + lane) * NB + b;
        int v = blkhist[idx];
        int s = v;
        #pragma unroll
        for (int d = 1; d <= 32; d <<= 1) {
            int u = __shfl_up(s, d, 64);
            if (lane >= d) s += u;
        }
        blkhist[idx] = run + s - v;      // exclusive offset of this block in b
        run += __shfl(s, 63, 64);
    }
    if (lane == 0) bcnt[b] = run;
}

// single-block exclusive scan with carry (handles arbitrary n in 1024-tiles)
__global__ __launch_bounds__(1024) void scan_kernel(
    const int* __restrict__ in, int* __restrict__ out, int n)
{
    __shared__ int buf[1024];
    __shared__ int carry;
    int t = threadIdx.x;
    if (t == 0) carry = 0;
    __syncthreads();
    for (int base = 0; base < n; base += 1024) {
        int v = (base + t < n) ? in[base + t] : 0;
        buf[t] = v;
        __syncthreads();
        for (int d = 1; d < 1024; d <<= 1) {
            int x = (t >= d) ? buf[t - d] : 0;
            __syncthreads();
            buf[t] += x;
            __syncthreads();
        }
        if (base + t < n) out[base + t] = carry + buf[t] - v;
        __syncthreads();
        if (t == 0) carry += buf[1023];
        __syncthreads();
    }
}

__global__ __launch_bounds__(256) void scatter_part_kernel(
    const int* __restrict__ src, const int* __restrict__ dst,
    const int* __restrict__ bbase, const int* __restrict__ blkhist,
    int* __restrict__ pairs, int E, int NB)
{
    __shared__ int base[MAXNB];
    __shared__ int cur[MAXNB];
    int t = threadIdx.x;
    for (int i = t; i < NB; i += 256) {
        base[i] = bbase[i] + blkhist[blockIdx.x * NB + i];
        cur[i] = 0;
    }
    __syncthreads();
    int chunk = (E + gridDim.x - 1) / gridDim.x;   // must match hist2d
    int beg = blockIdx.x * chunk;
    int end = min(E, beg + chunk);
    for (int i = beg + t; i < end; i += 256) {
        int d = dst[i], s = src[i];
        int b = d >> 7;
        int r = atomicAdd(&cur[b], 1);
        // pack: local dst (7b) in [31:24], src (24b) in [23:0]; requires N <= 2^24
        pairs[base[b] + r] = ((d & 127) << 24) | s;
    }
}

__global__ __launch_bounds__(256) void bucket_fill_kernel(
    const int* __restrict__ pairs, const int* __restrict__ bbase,
    const int* __restrict__ bcnt, int* __restrict__ row_start,
    int* __restrict__ counts, int* __restrict__ csr, int N)
{
    int b = blockIdx.x, n0 = b << 7;
    __shared__ int lhist[128], loff[128], lcur[128];
    int t = threadIdx.x;
    if (t < 128) { lhist[t] = 0; lcur[t] = 0; }
    __syncthreads();
    int base = bbase[b], cnt = bcnt[b];
    for (int i = t; i < cnt; i += 256)
        atomicAdd(&lhist[((unsigned)pairs[base + i]) >> 24], 1);
    __syncthreads();
    if (t < 64) {   // wave 0: scan 128 counts (2/lane), emit counts/row_start
        int c0 = lhist[2*t], c1 = lhist[2*t + 1];
        int tp = c0 + c1, s = tp;
        #pragma unroll
        for (int d = 1; d <= 32; d <<= 1) {
            int u = __shfl_up(s, d, 64);
            if (t >= d) s += u;
        }
        int excl = s - tp;
        loff[2*t] = excl; loff[2*t + 1] = excl + c0;
        int na = n0 + 2*t, nb2 = na + 1;
        if (na < N)  { row_start[na]  = base + excl;      counts[na]  = c0; }
        if (nb2 < N) { row_start[nb2] = base + excl + c0; counts[nb2] = c1; }
    }
    __syncthreads();
    for (int i = t; i < cnt; i += 256) {
        int w = pairs[base + i];
        int s = w & 0xFFFFFF, l = ((unsigned)w) >> 24;
        int p = atomicAdd(&lcur[l], 1);
        csr[base + loff[l] + p] = s;
    }
}

// ---- legacy fallback (round-0 behavior) ----
__global__ __launch_bounds__(256) void count_kernel(
    const int* __restrict__ dst, int* __restrict__ counts, int E)
{
    int e = blockIdx.x * 256 + threadIdx.x;
    if (e < E) atomicAdd(&counts[dst[e]], 1);
}

__global__ __launch_bounds__(256) void alloc_kernel(
    const int* __restrict__ counts, int* __restrict__ row_start,
    int* __restrict__ gcur, int N)
{
    int n = blockIdx.x * 256 + threadIdx.x;
    int lane = threadIdx.x & 63;
    int cnt = (n < N) ? counts[n] : 0;
    int s = cnt;
    #pragma unroll
    for (int d = 1; d <= 32; d <<= 1) {
        int t = __shfl_up(s, d, 64);
        if (lane >= d) s += t;
    }
    int total = __shfl(s, 63, 64);
    int base = 0;
    if (lane == 0) base = atomicAdd(gcur, total);
    base = __shfl(base, 0, 64);
    if (n < N) row_start[n] = base + s - cnt;
}

__global__ __launch_bounds__(256) void fill_kernel(
    const int* __restrict__ src, const int* __restrict__ dst,
    const int* __restrict__ row_start, int* __restrict__ cursor,
    int* __restrict__ csr, int E)
{
    int e = blockIdx.x * 256 + threadIdx.x;
    if (e < E) {
        int d = dst[e];
        int p = atomicAdd(&cursor[d], 1);
        csr[row_start[d] + p] = src[e];
    }
}

// ---------------- AGNN propagation: one wave per dst node -------------------------
// 16 edges per wave-iteration: 4 lanes per edge, each lane owns a float4
// feature quad (sub = lane&3). Dot = 4 FMA + 2 shfl steps. Softmax via
// CONSTANT shift M = |beta| (shift-invariant => identical to reference).
// Final merge: butterfly over edge-slots (lanes differing in bits 2..5).
__global__ __launch_bounds__(256) void prop_kernel(
    const float* __restrict__ f, const float* __restrict__ rn,
    const int* __restrict__ row_start, const int* __restrict__ counts,
    const int* __restrict__ csr, const void* __restrict__ beta_ptr, int use_beta,
    float* __restrict__ out, float* __restrict__ rn_out, int N,
    const int* __restrict__ flagp)
{
    int wid = blockIdx.x * 4 + (threadIdx.x >> 6);
    if (wid >= N) return;
    const int isf32 = *flagp;
    const int lane = threadIdx.x & 63;
    const int sub  = lane & 3;       // feature quad: features [sub*4, sub*4+4)
    const int es   = lane >> 2;      // edge slot within iteration (0..15)
    const int n = wid;

    const float beta = use_beta ? load_in(beta_ptr, 0, isf32) : 1.0f;
    const float M = fabsf(beta);
    const f32x4 fn_v = *(const f32x4*)&f[(size_t)n*HID + sub*4];
    const float rn_n = rn[n];
    const int base = row_start[n];
    const int deg  = counts[n];

    f32x4 acc = {0.f, 0.f, 0.f, 0.f};
    float s = 0.f;
    for (int j0 = 0; j0 < deg + 1; j0 += 16) {
        int j = j0 + es;
        int idx = base + ((j < deg) ? j : 0);   // address always in-bounds
        int v = csr[idx];
        int src = (j < deg) ? v : n;            // virtual self-loop at j==deg
        f32x4 fs = *(const f32x4*)&f[(size_t)src*HID + sub*4];
        float rs = rn[src];
        float p = fs[0]*fn_v[0] + fs[1]*fn_v[1] + fs[2]*fn_v[2] + fs[3]*fn_v[3];
        p += __shfl_xor(p, 1, 64);
        p += __shfl_xor(p, 2, 64);
        float alpha = beta * p * rs * rn_n;     // in [-|beta|, |beta|]
        float t = (j <= deg) ? __expf(alpha - M) : 0.f;   // in (0, 1]
        s += t;
        acc[0] += t*fs[0]; acc[1] += t*fs[1];
        acc[2] += t*fs[2]; acc[3] += t*fs[3];
    }
    // reduce across the 16 edge-slots (each edge's t lives on 4 lanes; lanes
    // sharing sub cover every slot exactly once => true totals per sub)
    #pragma unroll
    for (int off = 4; off <= 32; off <<= 1) {
        s      += __shfl_xor(s,      off, 64);
        acc[0] += __shfl_xor(acc[0], off, 64);
        acc[1] += __shfl_xor(acc[1], off, 64);
        acc[2] += __shfl_xor(acc[2], off, 64);
        acc[3] += __shfl_xor(acc[3], off, 64);
    }
    f32x4 o;
    o[0] = acc[0]/s; o[1] = acc[1]/s; o[2] = acc[2]/s; o[3] = acc[3]/s;
    if (lane < 4) *(f32x4*)&out[(size_t)n*HID + sub*4] = o;
    float p2 = o[0]*o[0] + o[1]*o[1] + o[2]*o[2] + o[3]*o[3];
    p2 += __shfl_xor(p2, 1, 64);
    p2 += __shfl_xor(p2, 2, 64);
    if (lane == 0) rn_out[n] = 1.0f / fmaxf(sqrtf(p2), 1e-12f);
}

// ---------------- classifier + log_softmax ----------------------------------------
__global__ __launch_bounds__(256) void classify_kernel(
    const float* __restrict__ h2, const void* __restrict__ W2,
    const void* __restrict__ b2, void* __restrict__ out, int N,
    const int* __restrict__ flagp)
{
    const int isf32 = *flagp;
    __shared__ float w2s[HID * NCLS];
    __shared__ float b2s[NCLS];
    for (int i = threadIdx.x; i < HID * NCLS; i += 256) w2s[i] = load_in(W2, i, isf32);
    if (threadIdx.x < NCLS) b2s[threadIdx.x] = load_in(b2, threadIdx.x, isf32);
    __syncthreads();

    int wid = blockIdx.x * 4 + (threadIdx.x >> 6);
    if (wid >= N) return;
    const int lane = threadIdx.x & 63;
    const int n = wid;

    float acc = -3.0e38f;
    if (lane < NCLS) {
        acc = b2s[lane];
        #pragma unroll
        for (int k = 0; k < HID; ++k)
            acc += h2[(size_t)n*HID + k] * w2s[k*NCLS + lane];
    }
    float mx = acc;
    #pragma unroll
    for (int off = 32; off >= 1; off >>= 1)
        mx = fmaxf(mx, __shfl_xor(mx, off, 64));
    float e = (lane < NCLS) ? __expf(acc - mx) : 0.f;
    float sum = e;
    #pragma unroll
    for (int off = 32; off >= 1; off >>= 1)
        sum += __shfl_xor(sum, off, 64);
    if (lane < NCLS) {
        float res = acc - mx - __logf(sum);
        if (!(res == res) || fabsf(res) > 1e30f) res = 0.f;
        size_t oi = (size_t)n*NCLS + lane;
        if (isf32) ((float*)out)[oi] = res;
        else       ((u16*)out)[oi]  = f2bf_rne(res);
    }
}

extern "C" void kernel_launch(void* const* d_in, const int* in_sizes, int n_in,
                              void* d_out, int out_size, void* d_ws, size_t ws_size,
                              hipStream_t stream)
{
    const void* x     = d_in[0];
    const int*  ei    = (const int*)d_in[1];
    const void* W1    = d_in[2];
    const void* b1    = d_in[3];
    const void* W2    = d_in[4];
    const void* b2    = d_in[5];
    const void* beta2 = d_in[6];

    const int N = in_sizes[0] / FIN;
    const int E = in_sizes[1] / 2;
    const int NB = (N + 127) >> 7;           // 128-node buckets
    const int* srcv = ei;
    const int* dstv = ei + E;

    char* ws = (char*)d_ws;
    size_t off = 0;
    auto take = [&](size_t bytes) -> char* {
        char* p = ws + off;
        off += (bytes + 255) & ~(size_t)255;
        return p;
    };
    // ---- minimal layout first ----
    float* h0        = (float*)take((size_t)N * HID * 4);
    float* rn0       = (float*)take((size_t)N * 4);
    // ---- zeroed range start (legacy path needs these zeroed) ----
    int*   counts    = (int*)take((size_t)N * 4);
    int*   cursor    = (int*)take((size_t)N * 4);
    int*   gcur      = (int*)take(256);
    // ---- zeroed range end ----
    int*   row_start = (int*)take((size_t)N * 4);
    int*   bcnt      = (int*)take((size_t)NB * 4);
    int*   bbase     = (int*)take((size_t)NB * 4);
    int*   csr       = (int*)take((size_t)(E + 64) * 4);
    int*   flag      = (int*)take(256);                   // NOT in memset range
    // ---- optional partition buffers: only used if they fit ws_size ----
    int*   pairs     = (int*)take((size_t)(E + 64) * 4);
    int*   blkhist   = (int*)take((size_t)NBLK * NB * 4);
    const int use_bucket = (off <= ws_size && NB <= MAXNB && N <= (1 << 24)) ? 1 : 0;

    // h1/rn1 live in d_out (dead before classify overwrites it); worst-case
    // d_out is bf16 -> 8MB >= 6.8MB needed.
    float* h1  = (float*)d_out;
    float* rn1 = (float*)((char*)d_out + (size_t)N * HID * 4);
    float* h2  = h0;   // h0 dead after prop1
    float* rn2 = rn0;  // sink for prop2's rnorm (unused)

    size_t zbytes = (size_t)((char*)gcur - (char*)counts) + 256;
    hipMemsetAsync(counts, 0, zbytes, stream);

    probe_kernel<<<1, 64, 0, stream>>>((const unsigned int*)x, flag);

    const int ngroups = (N + 15) / 16;
    gemm1_mfma<<<(ngroups + 3) / 4, 256, 0, stream>>>(x, W1, b1, h0, rn0, ngroups, N, flag);

    int eb = (E + 255) / 256;
    int nb = (N + 255) / 256;
    int wb = (N + 3) / 4;                       // one wave per node
    if (use_bucket) {
        hist2d_kernel<<<NBLK, 256, 0, stream>>>(dstv, blkhist, E, NB);
        scanB_kernel<<<(NB + 3) / 4, 256, 0, stream>>>(blkhist, bcnt, NB);
        scan_kernel<<<1, 1024, 0, stream>>>(bcnt, bbase, NB);
        scatter_part_kernel<<<NBLK, 256, 0, stream>>>(srcv, dstv, bbase, blkhist, pairs, E, NB);
        bucket_fill_kernel<<<NB, 256, 0, stream>>>(pairs, bbase, bcnt, row_start, counts, csr, N);
    } else {
        count_kernel<<<eb, 256, 0, stream>>>(dstv, counts, E);
        alloc_kernel<<<nb, 256, 0, stream>>>(counts, row_start, gcur, N);
        fill_kernel<<<eb, 256, 0, stream>>>(srcv, dstv, row_start, cursor, csr, E);
    }

    prop_kernel<<<wb, 256, 0, stream>>>(h0, rn0, row_start, counts, csr,
                                        b1, 0, h1, rn1, N, flag);
    prop_kernel<<<wb, 256, 0, stream>>>(h1, rn1, row_start, counts, csr,
                                        beta2, 1, h2, rn2, N, flag);

    classify_kernel<<<wb, 256, 0, stream>>>(h2, W2, b2, d_out, N, flag);
}

// Round 6
// 575.170 us; speedup vs baseline: 3.9807x; 1.0147x over previous
//
#include <hip/hip_runtime.h>
#include <hip/hip_bf16.h>

#define FIN 512
#define HID 16
#define NCLS 40
#define MAXNB 1024   // max buckets supported by LDS partition path
#define NBLK 256     // scatter/hist grid (must match between hist2d & scatter)

typedef unsigned short u16;
typedef __attribute__((ext_vector_type(8))) short short8;
typedef __attribute__((ext_vector_type(4))) float f32x4;

__device__ __forceinline__ float bf2f(u16 u) {
    return __uint_as_float(((unsigned int)u) << 16);
}
__device__ __forceinline__ u16 f2bf_rne(float f) {
    unsigned int u = __float_as_uint(f);
    unsigned int r = u + 0x7FFFu + ((u >> 16) & 1u);
    return (u16)(r >> 16);
}
// HW packed f32->bf16 RNE (identical rounding to f2bf_rne); T12 recipe, gfx950
__device__ __forceinline__ unsigned int cvt_pk_bf16(float lo, float hi) {
    unsigned int w;
    asm("v_cvt_pk_bf16_f32 %0, %1, %2" : "=v"(w) : "v"(lo), "v"(hi));
    return w;
}
// load element i of a float input that is either bf16 (isf32=0) or fp32 (isf32=1)
__device__ __forceinline__ float load_in(const void* p, size_t i, int isf32) {
    return isf32 ? ((const float*)p)[i] : bf2f(((const u16*)p)[i]);
}

// ---------------- dtype probe: bf16-packed vs fp32 words --------------------------
__global__ void probe_kernel(const unsigned int* __restrict__ x, int* __restrict__ flag)
{
    int cnt = 0;
    for (int i = threadIdx.x; i < 256; i += 64) {
        unsigned int w = x[i];
        float v = __uint_as_float((w & 0xFFFFu) << 16);
        float a = fabsf(v);
        if (a >= 6.1e-5f && a <= 64.f) cnt++;
    }
    #pragma unroll
    for (int off = 32; off >= 1; off >>= 1) cnt += __shfl_xor(cnt, off, 64);
    if (threadIdx.x == 0) *flag = (cnt < 128) ? 1 : 0;   // 1 => inputs are fp32
}

// ---------------- GEMM1: h = relu(x @ W1 + b1); rn = 1/max(||h_row||, eps) --------
// W1 fragments in LDS (shared by 4 waves). fp32 path converts via
// v_cvt_pk_bf16_f32 (1 op / 2 elems) instead of manual RNE (~4 ops/elem).
__global__ __launch_bounds__(256) void gemm1_mfma(
    const void* __restrict__ x, const void* __restrict__ W1, const void* __restrict__ b1,
    float* __restrict__ h, float* __restrict__ rn, int ngroups, int N,
    const int* __restrict__ flagp)
{
    const int isf32 = *flagp;
    __shared__ u16 w1s[8192];    // [kb][lane][j] bf16 fragments, 16 KB
    __shared__ float b1s[HID];
    const int lane = threadIdx.x & 63;
    const int m    = lane & 15;      // B col / D col
    const int quad = lane >> 4;

    // cooperative stage: w1s[kb*512 + ln*8 + j] = B[k=kb*32+(ln>>4)*8+j][ln&15]
    for (int i = threadIdx.x; i < 8192; i += 256) {
        int kb = i >> 9, rem = i & 511, ln = rem >> 3, j = rem & 7;
        int k = kb*32 + (ln >> 4)*8 + j;
        w1s[i] = f2bf_rne(load_in(W1, (size_t)k*HID + (ln & 15), isf32));
    }
    if (threadIdx.x < HID) b1s[threadIdx.x] = load_in(b1, threadIdx.x, isf32);
    __syncthreads();

    const int wid = blockIdx.x * 4 + (threadIdx.x >> 6);
    const int nw  = gridDim.x * 4;
    const float bias = b1s[m];

    for (int g = wid; g < ngroups; g += nw) {
        // clamp row for OOB-safety when N % 16 != 0 (stores are guarded below)
        size_t row = (size_t)g*16 + m;
        if (row >= (size_t)N) row = N - 1;
        f32x4 acc = {0.f, 0.f, 0.f, 0.f};
        if (isf32) {
            const float* xb = (const float*)x + row*FIN + quad*8;
            #pragma unroll
            for (int kb = 0; kb < 16; ++kb) {
                f32x4 v0 = *(const f32x4*)(xb + kb*32);
                f32x4 v1 = *(const f32x4*)(xb + kb*32 + 4);
                union { unsigned int u[4]; short8 s; } cv;
                cv.u[0] = cvt_pk_bf16(v0[0], v0[1]);
                cv.u[1] = cvt_pk_bf16(v0[2], v0[3]);
                cv.u[2] = cvt_pk_bf16(v1[0], v1[1]);
                cv.u[3] = cvt_pk_bf16(v1[2], v1[3]);
                short8 bf = *(const short8*)&w1s[kb*512 + lane*8];
                acc = __builtin_amdgcn_mfma_f32_16x16x32_bf16(cv.s, bf, acc, 0, 0, 0);
            }
        } else {
            const u16* xb = (const u16*)x + row*FIN + quad*8;
            #pragma unroll
            for (int kb = 0; kb < 16; ++kb) {
                short8 a = *(const short8*)(xb + kb*32);
                short8 bf = *(const short8*)&w1s[kb*512 + lane*8];
                acc = __builtin_amdgcn_mfma_f32_16x16x32_bf16(a, bf, acc, 0, 0, 0);
            }
        }
        // D: row = quad*4+i, col = m   [verified layout, m89/m91]
        #pragma unroll
        for (int i = 0; i < 4; ++i) {
            int r = quad*4 + i;
            float v = fmaxf(acc[i] + bias, 0.f);
            size_t orow = (size_t)g*16 + r;
            if (orow < (size_t)N) h[orow*HID + m] = v;
            float ss = v*v;
            ss += __shfl_xor(ss, 1, 64);
            ss += __shfl_xor(ss, 2, 64);
            ss += __shfl_xor(ss, 4, 64);
            ss += __shfl_xor(ss, 8, 64);
            if (m == 0 && orow < (size_t)N) rn[orow] = 1.0f / fmaxf(sqrtf(ss), 1e-12f);
        }
    }
}

// ---------------- CSR build (grouped by dst) — zero global atomics ----------------
__global__ __launch_bounds__(256) void hist2d_kernel(
    const int* __restrict__ dst, int* __restrict__ blkhist, int E, int NB)
{
    __shared__ int hist[MAXNB];
    int t = threadIdx.x;
    for (int i = t; i < NB; i += 256) hist[i] = 0;
    __syncthreads();
    int chunk = (E + gridDim.x - 1) / gridDim.x;
    int beg = blockIdx.x * chunk;
    int end = min(E, beg + chunk);
    for (int i = beg + t; i < end; i += 256)
        atomicAdd(&hist[dst[i] >> 7], 1);
    __syncthreads();
    for (int i = t; i < NB; i += 256)
        blkhist[blockIdx.x * NB + i] = hist[i];
}

__global__ __launch_bounds__(256) void scanB_kernel(
    int* __restrict__ blkhist, int* __restrict__ bcnt, int NB)
{
    int b = blockIdx.x * 4 + (threadIdx.x >> 6);
    if (b >= NB) return;
    int lane = threadIdx.x & 63;
    int run = 0;
    for (int i0 = 0; i0 < NBLK; i0 += 64) {
        int idx = (i0 + lane) * NB + b;
        int v = blkhist[idx];
        int s = v;
        #pragma unroll
        for (int d = 1; d <= 32; d <<= 1) {
            int u = __shfl_up(s, d, 64);
            if (lane >= d) s += u;
        }
        blkhist[idx] = run + s - v;      // exclusive offset of this block in b
        run += __shfl(s, 63, 64);
    }
    if (lane == 0) bcnt[b] = run;
}

// single-block exclusive scan with carry (handles arbitrary n in 1024-tiles)
__global__ __launch_bounds__(1024) void scan_kernel(
    const int* __restrict__ in, int* __restrict__ out, int n)
{
    __shared__ int buf[1024];
    __shared__ int carry;
    int t = threadIdx.x;
    if (t == 0) carry = 0;
    __syncthreads();
    for (int base = 0; base < n; base += 1024) {
        int v = (base + t < n) ? in[base + t] : 0;
        buf[t] = v;
        __syncthreads();
        for (int d = 1; d < 1024; d <<= 1) {
            int x = (t >= d) ? buf[t - d] : 0;
            __syncthreads();
            buf[t] += x;
            __syncthreads();
        }
        if (base + t < n) out[base + t] = carry + buf[t] - v;
        __syncthreads();
        if (t == 0) carry += buf[1023];
        __syncthreads();
    }
}

__global__ __launch_bounds__(256) void scatter_part_kernel(
    const int* __restrict__ src, const int* __restrict__ dst,
    const int* __restrict__ bbase, const int* __restrict__ blkhist,
    int* __restrict__ pairs, int E, int NB)
{
    __shared__ int base[MAXNB];
    __shared__ int cur[MAXNB];
    int t = threadIdx.x;
    for (int i = t; i < NB; i += 256) {
        base[i] = bbase[i] + blkhist[blockIdx.x * NB + i];
        cur[i] = 0;
    }
    __syncthreads();
    int chunk = (E + gridDim.x - 1) / gridDim.x;   // must match hist2d
    int beg = blockIdx.x * chunk;
    int end = min(E, beg + chunk);
    for (int i = beg + t; i < end; i += 256) {
        int d = dst[i], s = src[i];
        int b = d >> 7;
        int r = atomicAdd(&cur[b], 1);
        // pack: local dst (7b) in [31:24], src (24b) in [23:0]; requires N <= 2^24
        pairs[base[b] + r] = ((d & 127) << 24) | s;
    }
}

__global__ __launch_bounds__(256) void bucket_fill_kernel(
    const int* __restrict__ pairs, const int* __restrict__ bbase,
    const int* __restrict__ bcnt, int* __restrict__ row_start,
    int* __restrict__ counts, int* __restrict__ csr, int N)
{
    int b = blockIdx.x, n0 = b << 7;
    __shared__ int lhist[128], loff[128], lcur[128];
    int t = threadIdx.x;
    if (t < 128) { lhist[t] = 0; lcur[t] = 0; }
    __syncthreads();
    int base = bbase[b], cnt = bcnt[b];
    for (int i = t; i < cnt; i += 256)
        atomicAdd(&lhist[((unsigned)pairs[base + i]) >> 24], 1);
    __syncthreads();
    if (t < 64) {   // wave 0: scan 128 counts (2/lane), emit counts/row_start
        int c0 = lhist[2*t], c1 = lhist[2*t + 1];
        int tp = c0 + c1, s = tp;
        #pragma unroll
        for (int d = 1; d <= 32; d <<= 1) {
            int u = __shfl_up(s, d, 64);
            if (t >= d) s += u;
        }
        int excl = s - tp;
        loff[2*t] = excl; loff[2*t + 1] = excl + c0;
        int na = n0 + 2*t, nb2 = na + 1;
        if (na < N)  { row_start[na]  = base + excl;      counts[na]  = c0; }
        if (nb2 < N) { row_start[nb2] = base + excl + c0; counts[nb2] = c1; }
    }
    __syncthreads();
    for (int i = t; i < cnt; i += 256) {
        int w = pairs[base + i];
        int s = w & 0xFFFFFF, l = ((unsigned)w) >> 24;
        int p = atomicAdd(&lcur[l], 1);
        csr[base + loff[l] + p] = s;
    }
}

// ---- legacy fallback (round-0 behavior) ----
__global__ __launch_bounds__(256) void count_kernel(
    const int* __restrict__ dst, int* __restrict__ counts, int E)
{
    int e = blockIdx.x * 256 + threadIdx.x;
    if (e < E) atomicAdd(&counts[dst[e]], 1);
}

__global__ __launch_bounds__(256) void alloc_kernel(
    const int* __restrict__ counts, int* __restrict__ row_start,
    int* __restrict__ gcur, int N)
{
    int n = blockIdx.x * 256 + threadIdx.x;
    int lane = threadIdx.x & 63;
    int cnt = (n < N) ? counts[n] : 0;
    int s = cnt;
    #pragma unroll
    for (int d = 1; d <= 32; d <<= 1) {
        int t = __shfl_up(s, d, 64);
        if (lane >= d) s += t;
    }
    int total = __shfl(s, 63, 64);
    int base = 0;
    if (lane == 0) base = atomicAdd(gcur, total);
    base = __shfl(base, 0, 64);
    if (n < N) row_start[n] = base + s - cnt;
}

__global__ __launch_bounds__(256) void fill_kernel(
    const int* __restrict__ src, const int* __restrict__ dst,
    const int* __restrict__ row_start, int* __restrict__ cursor,
    int* __restrict__ csr, int E)
{
    int e = blockIdx.x * 256 + threadIdx.x;
    if (e < E) {
        int d = dst[e];
        int p = atomicAdd(&cursor[d], 1);
        csr[row_start[d] + p] = src[e];
    }
}

// ---------------- AGNN propagation (pass 1): one wave per dst node ----------------
// 16 edges per wave-iteration: 4 lanes per edge, lane owns a float4 feature quad.
// Softmax via CONSTANT shift M = |beta| (shift-invariant => identical to ref).
__global__ __launch_bounds__(256) void prop_kernel(
    const float* __restrict__ f, const float* __restrict__ rn,
    const int* __restrict__ row_start, const int* __restrict__ counts,
    const int* __restrict__ csr, const void* __restrict__ beta_ptr, int use_beta,
    float* __restrict__ out, float* __restrict__ rn_out, int N,
    const int* __restrict__ flagp)
{
    int wid = blockIdx.x * 4 + (threadIdx.x >> 6);
    if (wid >= N) return;
    const int isf32 = *flagp;
    const int lane = threadIdx.x & 63;
    const int sub  = lane & 3;       // feature quad: features [sub*4, sub*4+4)
    const int es   = lane >> 2;      // edge slot within iteration (0..15)
    const int n = wid;

    const float beta = use_beta ? load_in(beta_ptr, 0, isf32) : 1.0f;
    const float M = fabsf(beta);
    const f32x4 fn_v = *(const f32x4*)&f[(size_t)n*HID + sub*4];
    const float rn_n = rn[n];
    const int base = row_start[n];
    const int deg  = counts[n];

    f32x4 acc = {0.f, 0.f, 0.f, 0.f};
    float s = 0.f;
    for (int j0 = 0; j0 < deg + 1; j0 += 16) {
        int j = j0 + es;
        int idx = base + ((j < deg) ? j : 0);   // address always in-bounds
        int v = csr[idx];
        int src = (j < deg) ? v : n;            // virtual self-loop at j==deg
        f32x4 fs = *(const f32x4*)&f[(size_t)src*HID + sub*4];
        float rs = rn[src];
        float p = fs[0]*fn_v[0] + fs[1]*fn_v[1] + fs[2]*fn_v[2] + fs[3]*fn_v[3];
        p += __shfl_xor(p, 1, 64);
        p += __shfl_xor(p, 2, 64);
        float alpha = beta * p * rs * rn_n;     // in [-|beta|, |beta|]
        float t = (j <= deg) ? __expf(alpha - M) : 0.f;   // in (0, 1]
        s += t;
        acc[0] += t*fs[0]; acc[1] += t*fs[1];
        acc[2] += t*fs[2]; acc[3] += t*fs[3];
    }
    #pragma unroll
    for (int off = 4; off <= 32; off <<= 1) {
        s      += __shfl_xor(s,      off, 64);
        acc[0] += __shfl_xor(acc[0], off, 64);
        acc[1] += __shfl_xor(acc[1], off, 64);
        acc[2] += __shfl_xor(acc[2], off, 64);
        acc[3] += __shfl_xor(acc[3], off, 64);
    }
    f32x4 o;
    o[0] = acc[0]/s; o[1] = acc[1]/s; o[2] = acc[2]/s; o[3] = acc[3]/s;
    if (lane < 4) *(f32x4*)&out[(size_t)n*HID + sub*4] = o;
    float p2 = o[0]*o[0] + o[1]*o[1] + o[2]*o[2] + o[3]*o[3];
    p2 += __shfl_xor(p2, 1, 64);
    p2 += __shfl_xor(p2, 2, 64);
    if (lane == 0) rn_out[n] = 1.0f / fmaxf(sqrtf(p2), 1e-12f);
}

// ---------------- AGNN pass 2 fused with classifier + log_softmax -----------------
// Same prop body; epilogue broadcasts the 16 h2 values to all lanes (16 shfl),
// computes logits from LDS-resident W2/b2, and writes log-probs directly.
// Kills the h2 store+reload (25 MB) and the classify launch.
__global__ __launch_bounds__(256) void prop_cls_kernel(
    const float* __restrict__ f, const float* __restrict__ rn,
    const int* __restrict__ row_start, const int* __restrict__ counts,
    const int* __restrict__ csr, const void* __restrict__ beta_ptr,
    const void* __restrict__ W2, const void* __restrict__ b2,
    void* __restrict__ outp, int N, const int* __restrict__ flagp)
{
    const int isf32 = *flagp;
    __shared__ float w2s[HID * NCLS];
    __shared__ float b2s[NCLS];
    for (int i = threadIdx.x; i < HID * NCLS; i += 256) w2s[i] = load_in(W2, i, isf32);
    if (threadIdx.x < NCLS) b2s[threadIdx.x] = load_in(b2, threadIdx.x, isf32);
    __syncthreads();          // before any early return (all waves participate)

    int wid = blockIdx.x * 4 + (threadIdx.x >> 6);
    if (wid >= N) return;
    const int lane = threadIdx.x & 63;
    const int sub  = lane & 3;
    const int es   = lane >> 2;
    const int n = wid;

    const float beta = load_in(beta_ptr, 0, isf32);
    const float M = fabsf(beta);
    const f32x4 fn_v = *(const f32x4*)&f[(size_t)n*HID + sub*4];
    const float rn_n = rn[n];
    const int base = row_start[n];
    const int deg  = counts[n];

    f32x4 acc = {0.f, 0.f, 0.f, 0.f};
    float s = 0.f;
    for (int j0 = 0; j0 < deg + 1; j0 += 16) {
        int j = j0 + es;
        int idx = base + ((j < deg) ? j : 0);
        int v = csr[idx];
        int src = (j < deg) ? v : n;
        f32x4 fs = *(const f32x4*)&f[(size_t)src*HID + sub*4];
        float rs = rn[src];
        float p = fs[0]*fn_v[0] + fs[1]*fn_v[1] + fs[2]*fn_v[2] + fs[3]*fn_v[3];
        p += __shfl_xor(p, 1, 64);
        p += __shfl_xor(p, 2, 64);
        float alpha = beta * p * rs * rn_n;
        float t = (j <= deg) ? __expf(alpha - M) : 0.f;
        s += t;
        acc[0] += t*fs[0]; acc[1] += t*fs[1];
        acc[2] += t*fs[2]; acc[3] += t*fs[3];
    }
    #pragma unroll
    for (int off = 4; off <= 32; off <<= 1) {
        s      += __shfl_xor(s,      off, 64);
        acc[0] += __shfl_xor(acc[0], off, 64);
        acc[1] += __shfl_xor(acc[1], off, 64);
        acc[2] += __shfl_xor(acc[2], off, 64);
        acc[3] += __shfl_xor(acc[3], off, 64);
    }
    f32x4 o;
    o[0] = acc[0]/s; o[1] = acc[1]/s; o[2] = acc[2]/s; o[3] = acc[3]/s;

    // broadcast full h2 row (16 values) to every lane: h[s2*4+d] lives as o[d]
    // on lanes with sub==s2 (all totals identical after the butterfly)
    float hall[16];
    const int bl = lane & ~3;
    #pragma unroll
    for (int s2 = 0; s2 < 4; ++s2) {
        hall[s2*4+0] = __shfl(o[0], bl + s2, 64);
        hall[s2*4+1] = __shfl(o[1], bl + s2, 64);
        hall[s2*4+2] = __shfl(o[2], bl + s2, 64);
        hall[s2*4+3] = __shfl(o[3], bl + s2, 64);
    }
    float a2 = -3.0e38f;
    if (lane < NCLS) {
        a2 = b2s[lane];
        #pragma unroll
        for (int k = 0; k < HID; ++k)
            a2 += hall[k] * w2s[k*NCLS + lane];
    }
    float mx = a2;
    #pragma unroll
    for (int off = 32; off >= 1; off >>= 1)
        mx = fmaxf(mx, __shfl_xor(mx, off, 64));
    float e = (lane < NCLS) ? __expf(a2 - mx) : 0.f;
    float sum = e;
    #pragma unroll
    for (int off = 32; off >= 1; off >>= 1)
        sum += __shfl_xor(sum, off, 64);
    if (lane < NCLS) {
        float res = a2 - mx - __logf(sum);
        if (!(res == res) || fabsf(res) > 1e30f) res = 0.f;
        size_t oi = (size_t)n*NCLS + lane;
        if (isf32) ((float*)outp)[oi] = res;
        else       ((u16*)outp)[oi]  = f2bf_rne(res);
    }
}

extern "C" void kernel_launch(void* const* d_in, const int* in_sizes, int n_in,
                              void* d_out, int out_size, void* d_ws, size_t ws_size,
                              hipStream_t stream)
{
    const void* x     = d_in[0];
    const int*  ei    = (const int*)d_in[1];
    const void* W1    = d_in[2];
    const void* b1    = d_in[3];
    const void* W2    = d_in[4];
    const void* b2    = d_in[5];
    const void* beta2 = d_in[6];

    const int N = in_sizes[0] / FIN;
    const int E = in_sizes[1] / 2;
    const int NB = (N + 127) >> 7;           // 128-node buckets
    const int* srcv = ei;
    const int* dstv = ei + E;

    char* ws = (char*)d_ws;
    size_t off = 0;
    auto take = [&](size_t bytes) -> char* {
        char* p = ws + off;
        off += (bytes + 255) & ~(size_t)255;
        return p;
    };
    // ---- minimal layout first ----
    float* h0        = (float*)take((size_t)N * HID * 4);
    float* rn0       = (float*)take((size_t)N * 4);
    float* h1        = (float*)take((size_t)N * HID * 4);   // ws now (d_out is live
    float* rn1       = (float*)take((size_t)N * 4);         // during fused prop2)
    // ---- zeroed range start (legacy path needs these zeroed) ----
    int*   counts    = (int*)take((size_t)N * 4);
    int*   cursor    = (int*)take((size_t)N * 4);
    int*   gcur      = (int*)take(256);
    // ---- zeroed range end ----
    int*   row_start = (int*)take((size_t)N * 4);
    int*   bcnt      = (int*)take((size_t)NB * 4);
    int*   bbase     = (int*)take((size_t)NB * 4);
    int*   csr       = (int*)take((size_t)(E + 64) * 4);
    int*   flag      = (int*)take(256);                   // NOT in memset range
    // ---- optional partition buffers: only used if they fit ws_size ----
    int*   pairs     = (int*)take((size_t)(E + 64) * 4);
    int*   blkhist   = (int*)take((size_t)NBLK * NB * 4);
    const int use_bucket = (off <= ws_size && NB <= MAXNB && N <= (1 << 24)) ? 1 : 0;

    size_t zbytes = (size_t)((char*)gcur - (char*)counts) + 256;
    hipMemsetAsync(counts, 0, zbytes, stream);

    probe_kernel<<<1, 64, 0, stream>>>((const unsigned int*)x, flag);

    const int ngroups = (N + 15) / 16;
    gemm1_mfma<<<(ngroups + 3) / 4, 256, 0, stream>>>(x, W1, b1, h0, rn0, ngroups, N, flag);

    int eb = (E + 255) / 256;
    int nb = (N + 255) / 256;
    int wb = (N + 3) / 4;                       // one wave per node
    if (use_bucket) {
        hist2d_kernel<<<NBLK, 256, 0, stream>>>(dstv, blkhist, E, NB);
        scanB_kernel<<<(NB + 3) / 4, 256, 0, stream>>>(blkhist, bcnt, NB);
        scan_kernel<<<1, 1024, 0, stream>>>(bcnt, bbase, NB);
        scatter_part_kernel<<<NBLK, 256, 0, stream>>>(srcv, dstv, bbase, blkhist, pairs, E, NB);
        bucket_fill_kernel<<<NB, 256, 0, stream>>>(pairs, bbase, bcnt, row_start, counts, csr, N);
    } else {
        count_kernel<<<eb, 256, 0, stream>>>(dstv, counts, E);
        alloc_kernel<<<nb, 256, 0, stream>>>(counts, row_start, gcur, N);
        fill_kernel<<<eb, 256, 0, stream>>>(srcv, dstv, row_start, cursor, csr, E);
    }

    prop_kernel<<<wb, 256, 0, stream>>>(h0, rn0, row_start, counts, csr,
                                        b1, 0, h1, rn1, N, flag);
    prop_cls_kernel<<<wb, 256, 0, stream>>>(h1, rn1, row_start, counts, csr,
                                            beta2, W2, b2, d_out, N, flag);
}